// Round 1
// baseline (1190.859 us; speedup 1.0000x reference)
//
#include <hip/hip_runtime.h>
#include <hip/hip_bf16.h>

// ---------------------------------------------------------------------------
// Mamba block forward, fp32 baseline.
// B=2 L=1024 D_MODEL=1024 D_INNER=2048 D_STATE=16 D_CONV=4 DT_RANK=64
// Pipeline:
//   1. xz = x @ W_in                      (2048 x 4096 x 1024 GEMM)
//   2. u_c = silu(depthwise_conv4(u)+cb)  (u = xz[:, :2048])
//   3. x_dbl = u_c @ W_x                  (2048 x 96 x 2048 GEMM)
//   4. dt = softplus(x_dbl[:, :64] @ W_dt + b_dt)   (2048 x 2048 x 64 GEMM)
//   5. selective scan (seq-sequential), fused epilogue:
//        y = (scan_y + u_c*D) * silu(z), written in-place over dt buffer
//   6. out = y @ W_out                    (2048 x 1024 x 2048 GEMM)
// ---------------------------------------------------------------------------

#define BM 64
#define BN 64
#define BK 16

__global__ __launch_bounds__(256) void gemm_f32(
    const float* __restrict__ A, const float* __restrict__ B,
    float* __restrict__ C, int M, int N, int K,
    int lda, int ldb, int ldc, int mode, const float* __restrict__ bias)
{
    __shared__ __align__(16) float As[BK][BM];
    __shared__ __align__(16) float Bs[BK][BN];

    const int tid = threadIdx.x;
    const int bm = blockIdx.y * BM;
    const int bn = blockIdx.x * BN;

    // A tile load: thread -> (m = tid/4, k = (tid%4)*4), float4 along K
    const int am = tid >> 2;
    const int ak = (tid & 3) << 2;
    // B tile load: thread -> (k = tid/16, n = (tid%16)*4), float4 along N
    const int bk = tid >> 4;
    const int bnn = (tid & 15) << 2;

    const int tx = tid & 15, ty = tid >> 4;
    const int rm = ty << 2;          // local row base
    const int rn = tx << 2;          // local col base
    const int cm = bm + rm, cn = bn + rn;

    float acc[4][4] = {};

    for (int k0 = 0; k0 < K; k0 += BK) {
        // ---- load A tile (M,K always in-bounds: M%64==0, K%16==0) ----
        const float* ap = A + (size_t)(bm + am) * lda + (k0 + ak);
        float4 av = *(const float4*)ap;
        As[ak + 0][am] = av.x;
        As[ak + 1][am] = av.y;
        As[ak + 2][am] = av.z;
        As[ak + 3][am] = av.w;
        // ---- load B tile with N guard ----
        {
            const int ncol = bn + bnn;
            const float* bp = B + (size_t)(k0 + bk) * ldb + ncol;
            float4 bv;
            if (ncol + 3 < N) {
                bv = *(const float4*)bp;
            } else {
                bv.x = (ncol + 0 < N) ? bp[0] : 0.f;
                bv.y = (ncol + 1 < N) ? bp[1] : 0.f;
                bv.z = (ncol + 2 < N) ? bp[2] : 0.f;
                bv.w = (ncol + 3 < N) ? bp[3] : 0.f;
            }
            *(float4*)&Bs[bk][bnn] = bv;
        }
        __syncthreads();

        #pragma unroll
        for (int k = 0; k < BK; ++k) {
            float4 a = *(const float4*)&As[k][rm];
            float4 b = *(const float4*)&Bs[k][rn];
            acc[0][0] += a.x * b.x; acc[0][1] += a.x * b.y;
            acc[0][2] += a.x * b.z; acc[0][3] += a.x * b.w;
            acc[1][0] += a.y * b.x; acc[1][1] += a.y * b.y;
            acc[1][2] += a.y * b.z; acc[1][3] += a.y * b.w;
            acc[2][0] += a.z * b.x; acc[2][1] += a.z * b.y;
            acc[2][2] += a.z * b.z; acc[2][3] += a.z * b.w;
            acc[3][0] += a.w * b.x; acc[3][1] += a.w * b.y;
            acc[3][2] += a.w * b.z; acc[3][3] += a.w * b.w;
        }
        __syncthreads();
    }

    #pragma unroll
    for (int i = 0; i < 4; ++i) {
        float* crow = C + (size_t)(cm + i) * ldc;
        #pragma unroll
        for (int j = 0; j < 4; ++j) {
            int col = cn + j;
            if (col < N) {
                float v = acc[i][j];
                if (mode == 1) {
                    v += bias[col];
                    v = (v > 20.f) ? v : logf(1.f + expf(v));  // softplus
                }
                crow[col] = v;
            }
        }
    }
}

// Depthwise causal conv (width 4) + bias + SiLU.
// u lives in xz[:, 0:2048] (row stride 4096). Output uc (row stride 2048).
__global__ __launch_bounds__(256) void conv_silu_kernel(
    const float* __restrict__ xz, const float* __restrict__ cw,
    const float* __restrict__ cb, float* __restrict__ uc)
{
    int idx = blockIdx.x * 256 + threadIdx.x;   // idx = r*2048 + d
    int d = idx & 2047;
    int r = idx >> 11;          // global row (b*1024 + l)
    int l = r & 1023;           // position within batch

    float4 w4 = *(const float4*)(cw + 4 * d);
    float w[4] = { w4.x, w4.y, w4.z, w4.w };
    float acc = cb[d];
    const float* up = xz + (size_t)r * 4096 + d;
    if (l >= 3) {
        acc += w[0] * up[-3 * 4096] + w[1] * up[-2 * 4096]
             + w[2] * up[-1 * 4096] + w[3] * up[0];
    } else {
        #pragma unroll
        for (int j = 0; j < 4; ++j) {
            int lj = l - 3 + j;
            if (lj >= 0) acc += w[j] * up[(j - 3) * 4096];
        }
    }
    float sig = 1.f / (1.f + expf(-acc));
    uc[idx] = acc * sig;
}

// Selective scan. One thread per (batch, channel); h[16] in registers.
// Chunked LDS staging of u / dt / z / (B,C). Fused output epilogue:
//   y = (scan_y + u*D[d]) * silu(z), stored IN PLACE over the dt buffer.
#define SC_CH 64
#define SC_T  32
__global__ __launch_bounds__(64) void scan_kernel(
    const float* __restrict__ uc,     // [2048][2048]
    float* __restrict__ dtb,          // [2048][2048]  in: dt, out: y
    const float* __restrict__ xz,     // z at [r][2048+d], row stride 4096
    const float* __restrict__ xdbl,   // [2048][96], B at col 64, C at col 80
    const float* __restrict__ A_log,  // [2048][16]
    const float* __restrict__ Dvec)   // [2048]
{
    __shared__ __align__(16) float s_u[SC_T][SC_CH];
    __shared__ __align__(16) float s_dt[SC_T][SC_CH];
    __shared__ __align__(16) float s_z[SC_T][SC_CH];
    __shared__ __align__(16) float s_bc[SC_T][32];   // [t][0:16]=B, [16:32]=C

    const int tid = threadIdx.x;
    const int bb = blockIdx.x >> 5;             // batch (32 blocks per batch)
    const int dbase = (blockIdx.x & 31) * SC_CH;
    const int d = dbase + tid;

    float A2[16];
    #pragma unroll
    for (int n = 0; n < 16; ++n)
        A2[n] = -expf(A_log[d * 16 + n]) * 1.44269504f;   // fold log2(e)
    const float Dd = Dvec[d];

    float h[16] = {};
    const size_t rowbase = (size_t)bb * 1024;

    for (int t0 = 0; t0 < 1024; t0 += SC_T) {
        // ---- cooperative staging ----
        for (int i = tid; i < SC_T * (SC_CH / 4); i += 64) {
            int tt = i / (SC_CH / 4);
            int cc = (i % (SC_CH / 4)) * 4;
            size_t r = rowbase + t0 + tt;
            *(float4*)&s_u[tt][cc]  = *(const float4*)&uc[r * 2048 + dbase + cc];
            *(float4*)&s_dt[tt][cc] = *(const float4*)&dtb[r * 2048 + dbase + cc];
            *(float4*)&s_z[tt][cc]  = *(const float4*)&xz[r * 4096 + 2048 + dbase + cc];
        }
        for (int i = tid; i < SC_T * 8; i += 64) {
            int tt = i / 8;
            int cc = (i % 8) * 4;
            size_t r = rowbase + t0 + tt;
            *(float4*)&s_bc[tt][cc] = *(const float4*)&xdbl[r * 96 + 64 + cc];
        }
        __syncthreads();

        #pragma unroll 1
        for (int t = 0; t < SC_T; ++t) {
            float dtv = s_dt[t][tid];
            float uv  = s_u[t][tid];
            float zv  = s_z[t][tid];
            float dtu = dtv * uv;
            float acc = 0.f;
            #pragma unroll
            for (int n = 0; n < 16; ++n) {
                float dA = exp2f(dtv * A2[n]);         // exp(dt*A)
                h[n] = dA * h[n] + dtu * s_bc[t][n];   // dA*h + dt*u*B
                acc += h[n] * s_bc[t][16 + n];         // dot(h, C)
            }
            float yv = acc + uv * Dd;
            float sig = 1.f / (1.f + expf(-zv));
            yv *= zv * sig;                            // * silu(z)
            dtb[(rowbase + t0 + t) * 2048 + d] = yv;   // in-place over dt
        }
        __syncthreads();
    }
}

extern "C" void kernel_launch(void* const* d_in, const int* in_sizes, int n_in,
                              void* d_out, int out_size, void* d_ws, size_t ws_size,
                              hipStream_t stream)
{
    const float* x      = (const float*)d_in[0];
    const float* W_in   = (const float*)d_in[1];
    const float* conv_w = (const float*)d_in[2];
    const float* conv_b = (const float*)d_in[3];
    const float* W_x    = (const float*)d_in[4];
    const float* W_dt   = (const float*)d_in[5];
    const float* b_dt   = (const float*)d_in[6];
    const float* A_log  = (const float*)d_in[7];
    const float* Dv     = (const float*)d_in[8];
    const float* W_out  = (const float*)d_in[9];
    float* out = (float*)d_out;

    float* ws   = (float*)d_ws;
    float* xz   = ws;                       // 2048*4096 = 8388608 floats
    float* uc   = xz + 8388608;             // 2048*2048 = 4194304
    float* xdbl = uc + 4194304;             // 2048*96   = 196608
    float* dtb  = xdbl + 196608;            // 2048*2048 = 4194304  (dt -> y)

    dim3 blk(256);

    // 1. xz = x @ W_in
    gemm_f32<<<dim3(4096 / BN, 2048 / BM), blk, 0, stream>>>(
        x, W_in, xz, 2048, 4096, 1024, 1024, 4096, 4096, 0, nullptr);

    // 2. u_c = silu(conv(u) + cb)
    conv_silu_kernel<<<(2048 * 2048) / 256, blk, 0, stream>>>(
        xz, conv_w, conv_b, uc);

    // 3. x_dbl = u_c @ W_x
    gemm_f32<<<dim3(2, 2048 / BM), blk, 0, stream>>>(
        uc, W_x, xdbl, 2048, 96, 2048, 2048, 96, 96, 0, nullptr);

    // 4. dt = softplus(x_dbl[:, :64] @ W_dt + b_dt)
    gemm_f32<<<dim3(2048 / BN, 2048 / BM), blk, 0, stream>>>(
        xdbl, W_dt, dtb, 2048, 2048, 64, 96, 2048, 2048, 1, b_dt);

    // 5. selective scan + fused epilogue (y overwrites dtb)
    scan_kernel<<<64, 64, 0, stream>>>(uc, dtb, xz, xdbl, A_log, Dv);

    // 6. out = y @ W_out
    gemm_f32<<<dim3(1024 / BN, 2048 / BM), blk, 0, stream>>>(
        dtb, W_out, out, 2048, 1024, 2048, 2048, 1024, 1024, 0, nullptr);
}

// Round 2
// 935.555 us; speedup vs baseline: 1.2729x; 1.2729x over previous
//
#include <hip/hip_runtime.h>
#include <hip/hip_bf16.h>

// ---------------------------------------------------------------------------
// Mamba block forward, fp32. Round 2: state-parallel scan (lane per (b,d,n)).
// B=2 L=1024 D_MODEL=1024 D_INNER=2048 D_STATE=16 D_CONV=4 DT_RANK=64
// ---------------------------------------------------------------------------

#define BM 64
#define BN 64
#define BK 16

__global__ __launch_bounds__(256) void gemm_f32(
    const float* __restrict__ A, const float* __restrict__ B,
    float* __restrict__ C, int M, int N, int K,
    int lda, int ldb, int ldc, int mode, const float* __restrict__ bias)
{
    __shared__ __align__(16) float As[BK][BM];
    __shared__ __align__(16) float Bs[BK][BN];

    const int tid = threadIdx.x;
    const int bm = blockIdx.y * BM;
    const int bn = blockIdx.x * BN;

    const int am = tid >> 2;
    const int ak = (tid & 3) << 2;
    const int bk = tid >> 4;
    const int bnn = (tid & 15) << 2;

    const int tx = tid & 15, ty = tid >> 4;
    const int rm = ty << 2;
    const int rn = tx << 2;
    const int cm = bm + rm, cn = bn + rn;

    float acc[4][4] = {};

    for (int k0 = 0; k0 < K; k0 += BK) {
        const float* ap = A + (size_t)(bm + am) * lda + (k0 + ak);
        float4 av = *(const float4*)ap;
        As[ak + 0][am] = av.x;
        As[ak + 1][am] = av.y;
        As[ak + 2][am] = av.z;
        As[ak + 3][am] = av.w;
        {
            const int ncol = bn + bnn;
            const float* bp = B + (size_t)(k0 + bk) * ldb + ncol;
            float4 bv;
            if (ncol + 3 < N) {
                bv = *(const float4*)bp;
            } else {
                bv.x = (ncol + 0 < N) ? bp[0] : 0.f;
                bv.y = (ncol + 1 < N) ? bp[1] : 0.f;
                bv.z = (ncol + 2 < N) ? bp[2] : 0.f;
                bv.w = (ncol + 3 < N) ? bp[3] : 0.f;
            }
            *(float4*)&Bs[bk][bnn] = bv;
        }
        __syncthreads();

        #pragma unroll
        for (int k = 0; k < BK; ++k) {
            float4 a = *(const float4*)&As[k][rm];
            float4 b = *(const float4*)&Bs[k][rn];
            acc[0][0] += a.x * b.x; acc[0][1] += a.x * b.y;
            acc[0][2] += a.x * b.z; acc[0][3] += a.x * b.w;
            acc[1][0] += a.y * b.x; acc[1][1] += a.y * b.y;
            acc[1][2] += a.y * b.z; acc[1][3] += a.y * b.w;
            acc[2][0] += a.z * b.x; acc[2][1] += a.z * b.y;
            acc[2][2] += a.z * b.z; acc[2][3] += a.z * b.w;
            acc[3][0] += a.w * b.x; acc[3][1] += a.w * b.y;
            acc[3][2] += a.w * b.z; acc[3][3] += a.w * b.w;
        }
        __syncthreads();
    }

    #pragma unroll
    for (int i = 0; i < 4; ++i) {
        float* crow = C + (size_t)(cm + i) * ldc;
        #pragma unroll
        for (int j = 0; j < 4; ++j) {
            int col = cn + j;
            if (col < N) {
                float v = acc[i][j];
                if (mode == 1) {
                    v += bias[col];
                    v = (v > 20.f) ? v : logf(1.f + expf(v));  // softplus
                }
                crow[col] = v;
            }
        }
    }
}

// Depthwise causal conv (width 4) + bias + SiLU.
__global__ __launch_bounds__(256) void conv_silu_kernel(
    const float* __restrict__ xz, const float* __restrict__ cw,
    const float* __restrict__ cb, float* __restrict__ uc)
{
    int idx = blockIdx.x * 256 + threadIdx.x;   // idx = r*2048 + d
    int d = idx & 2047;
    int r = idx >> 11;
    int l = r & 1023;

    float4 w4 = *(const float4*)(cw + 4 * d);
    float w[4] = { w4.x, w4.y, w4.z, w4.w };
    float acc = cb[d];
    const float* up = xz + (size_t)r * 4096 + d;
    if (l >= 3) {
        acc += w[0] * up[-3 * 4096] + w[1] * up[-2 * 4096]
             + w[2] * up[-1 * 4096] + w[3] * up[0];
    } else {
        #pragma unroll
        for (int j = 0; j < 4; ++j) {
            int lj = l - 3 + j;
            if (lj >= 0) acc += w[j] * up[(j - 3) * 4096];
        }
    }
    float sig = 1.f / (1.f + expf(-acc));
    uc[idx] = acc * sig;
}

// ---------------------------------------------------------------------------
// Selective scan v2: one LANE per (batch, channel, state).
// Wave = 4 channels x 16 states. Block = 4 waves = 16 channels.
// Grid = 2 batches x 128 channel-groups = 256 blocks (1024 waves total).
// Critical path per step is a single FMA (h = dA*h + dtu*B); exp2 and B/C
// loads are off-path. y_t via 4-step __shfl_xor butterfly over 16 lanes.
// Fused epilogue: y = (scan_y + u*D) * silu(z), in-place over dt buffer.
// ---------------------------------------------------------------------------
#define SCB_CH 16   // channels per block
#define SCB_T  64   // timesteps per LDS chunk
__global__ __launch_bounds__(256) void scan_kernel2(
    const float* __restrict__ uc,     // [2048][2048]
    float* __restrict__ dtb,          // [2048][2048]  in: dt, out: y
    const float* __restrict__ xz,     // z at [r][2048+d], row stride 4096
    const float* __restrict__ xdbl,   // [2048][96], B at col 64, C at col 80
    const float* __restrict__ A_log,  // [2048][16]
    const float* __restrict__ Dvec)   // [2048]
{
    __shared__ __align__(16) float s_u [SCB_T][SCB_CH];
    __shared__ __align__(16) float s_dt[SCB_T][SCB_CH];
    __shared__ __align__(16) float s_z [SCB_T][SCB_CH];
    __shared__ __align__(16) float s_bc[SCB_T][32];   // [t][0:16]=B, [16:32]=C
    __shared__ __align__(16) float s_y [SCB_T][SCB_CH];

    const int tid  = threadIdx.x;          // 0..255
    const int wave = tid >> 6;             // 0..3
    const int lane = tid & 63;
    const int cg   = lane >> 4;            // channel within wave, 0..3
    const int n    = lane & 15;            // state index
    const int ch   = wave * 4 + cg;        // channel within block, 0..15
    const int bb   = blockIdx.x >> 7;      // batch
    const int dbase = (blockIdx.x & 127) * SCB_CH;
    const int d    = dbase + ch;

    const float A2 = -expf(A_log[d * 16 + n]) * 1.44269504f;  // fold log2(e)
    const float Dd = Dvec[d];

    float h = 0.f;
    const size_t rowbase = (size_t)bb * 1024;

    for (int t0 = 0; t0 < 1024; t0 += SCB_T) {
        // ---- cooperative staging (16 floats/row for u,dt,z; 32 for B,C) ----
        for (int i = tid; i < SCB_T * 4; i += 256) {
            int tt = i >> 2; int cc = (i & 3) << 2;
            size_t r = rowbase + t0 + tt;
            *(float4*)&s_u [tt][cc] = *(const float4*)&uc [r * 2048 + dbase + cc];
            *(float4*)&s_dt[tt][cc] = *(const float4*)&dtb[r * 2048 + dbase + cc];
            *(float4*)&s_z [tt][cc] = *(const float4*)&xz [r * 4096 + 2048 + dbase + cc];
        }
        for (int i = tid; i < SCB_T * 8; i += 256) {
            int tt = i >> 3; int cc = (i & 7) << 2;
            size_t r = rowbase + t0 + tt;
            *(float4*)&s_bc[tt][cc] = *(const float4*)&xdbl[r * 96 + 64 + cc];
        }
        __syncthreads();

        #pragma unroll 4
        for (int t = 0; t < SCB_T; ++t) {
            float dtv = s_dt[t][ch];        // LDS broadcast within 16-lane group
            float uv  = s_u[t][ch];
            float dA  = exp2f(dtv * A2);    // off critical path
            float bn  = s_bc[t][n];
            float cn  = s_bc[t][16 + n];
            h = dA * h + (dtv * uv) * bn;   // the only serial dependence
            float p = h * cn;
            p += __shfl_xor(p, 1);
            p += __shfl_xor(p, 2);
            p += __shfl_xor(p, 4);
            p += __shfl_xor(p, 8);          // all 16 lanes now hold sum
            if (n == 0) {
                float zv = s_z[t][ch];
                float yv = p + uv * Dd;
                yv *= zv / (1.f + expf(-zv));   // * silu(z)
                s_y[t][ch] = yv;
            }
        }
        __syncthreads();

        // ---- write y chunk back (in-place over dt buffer) ----
        for (int i = tid; i < SCB_T * 4; i += 256) {
            int tt = i >> 2; int cc = (i & 3) << 2;
            size_t r = rowbase + t0 + tt;
            *(float4*)&dtb[r * 2048 + dbase + cc] = *(const float4*)&s_y[tt][cc];
        }
        __syncthreads();
    }
}

extern "C" void kernel_launch(void* const* d_in, const int* in_sizes, int n_in,
                              void* d_out, int out_size, void* d_ws, size_t ws_size,
                              hipStream_t stream)
{
    const float* x      = (const float*)d_in[0];
    const float* W_in   = (const float*)d_in[1];
    const float* conv_w = (const float*)d_in[2];
    const float* conv_b = (const float*)d_in[3];
    const float* W_x    = (const float*)d_in[4];
    const float* W_dt   = (const float*)d_in[5];
    const float* b_dt   = (const float*)d_in[6];
    const float* A_log  = (const float*)d_in[7];
    const float* Dv     = (const float*)d_in[8];
    const float* W_out  = (const float*)d_in[9];
    float* out = (float*)d_out;

    float* ws   = (float*)d_ws;
    float* xz   = ws;                       // 2048*4096 floats
    float* uc   = xz + 8388608;             // 2048*2048
    float* xdbl = uc + 4194304;             // 2048*96
    float* dtb  = xdbl + 196608;            // 2048*2048  (dt -> y)

    dim3 blk(256);

    // 1. xz = x @ W_in
    gemm_f32<<<dim3(4096 / BN, 2048 / BM), blk, 0, stream>>>(
        x, W_in, xz, 2048, 4096, 1024, 1024, 4096, 4096, 0, nullptr);

    // 2. u_c = silu(conv(u) + cb)
    conv_silu_kernel<<<(2048 * 2048) / 256, blk, 0, stream>>>(
        xz, conv_w, conv_b, uc);

    // 3. x_dbl = u_c @ W_x
    gemm_f32<<<dim3(2, 2048 / BM), blk, 0, stream>>>(
        uc, W_x, xdbl, 2048, 96, 2048, 2048, 96, 96, 0, nullptr);

    // 4. dt = softplus(x_dbl[:, :64] @ W_dt + b_dt)
    gemm_f32<<<dim3(2048 / BN, 2048 / BM), blk, 0, stream>>>(
        xdbl, W_dt, dtb, 2048, 2048, 64, 96, 2048, 2048, 1, b_dt);

    // 5. selective scan + fused epilogue (y overwrites dtb)
    scan_kernel2<<<256, 256, 0, stream>>>(uc, dtb, xz, xdbl, A_log, Dv);

    // 6. out = y @ W_out
    gemm_f32<<<dim3(1024 / BN, 2048 / BM), blk, 0, stream>>>(
        dtb, W_out, out, 2048, 1024, 2048, 2048, 1024, 1024, 0, nullptr);
}

// Round 3
// 639.918 us; speedup vs baseline: 1.8610x; 1.4620x over previous
//
#include <hip/hip_runtime.h>
#include <hip/hip_bf16.h>

// ---------------------------------------------------------------------------
// Mamba block forward. Round 3: bf16 MFMA for GEMM1 (x@W_in) and GEMM6
// (y@W_out); fp32 elsewhere. B=2 L=1024 DM=1024 DI=2048 DS=16 DC=4 DTR=64
// ---------------------------------------------------------------------------

typedef __attribute__((ext_vector_type(8))) short bfrag;
typedef __attribute__((ext_vector_type(4))) float f32x4;

__device__ __forceinline__ unsigned short f2bf(float f) {
    unsigned int u = __float_as_uint(f);
    u += 0x7FFF + ((u >> 16) & 1);          // round-to-nearest-even
    return (unsigned short)(u >> 16);
}

// ---------------- bf16 MFMA GEMM: C[M][N] = A[M][K] * BT[N][K]^T ------------
// 128x128 tile, 4 waves, each wave 64x64 via 4x4 grid of 16x16x32 MFMA.
__global__ __launch_bounds__(256) void gemm_bf16(
    const unsigned short* __restrict__ A,   // [M][K] bf16
    const unsigned short* __restrict__ BT,  // [N][K] bf16
    float* __restrict__ C,                  // [M][N] fp32
    int K, int lda, int ldb, int ldc)
{
    __shared__ unsigned short sA[128][40];  // +8 pad: frag-read 2-way max
    __shared__ unsigned short sB[128][40];

    const int tid  = threadIdx.x;
    const int wave = tid >> 6, lane = tid & 63;
    const int lm   = lane & 15;
    const int quad = lane >> 4;
    const int kb   = quad << 3;             // 0,8,16,24
    const int wrow = (wave >> 1) << 6;      // 0 / 64
    const int wcol = (wave & 1) << 6;       // 0 / 64
    const int bm = blockIdx.y * 128, bn = blockIdx.x * 128;

    const int srow = tid >> 2;              // 0..63
    const int scol = (tid & 3) << 3;        // 0,8,16,24

    f32x4 acc[4][4];
    #pragma unroll
    for (int i = 0; i < 4; ++i)
        #pragma unroll
        for (int j = 0; j < 4; ++j) {
            acc[i][j][0] = 0.f; acc[i][j][1] = 0.f;
            acc[i][j][2] = 0.f; acc[i][j][3] = 0.f;
        }

    for (int k0 = 0; k0 < K; k0 += 32) {
        // stage A/B tiles: each thread 16B x 4 (two 64-row rounds each)
        *(float4*)&sA[srow][scol]      = *(const float4*)&A [(size_t)(bm + srow)      * lda + k0 + scol];
        *(float4*)&sA[srow + 64][scol] = *(const float4*)&A [(size_t)(bm + srow + 64) * lda + k0 + scol];
        *(float4*)&sB[srow][scol]      = *(const float4*)&BT[(size_t)(bn + srow)      * ldb + k0 + scol];
        *(float4*)&sB[srow + 64][scol] = *(const float4*)&BT[(size_t)(bn + srow + 64) * ldb + k0 + scol];
        __syncthreads();

        bfrag af[4], bf[4];
        #pragma unroll
        for (int i = 0; i < 4; ++i) af[i] = *(const bfrag*)&sA[wrow + i * 16 + lm][kb];
        #pragma unroll
        for (int j = 0; j < 4; ++j) bf[j] = *(const bfrag*)&sB[wcol + j * 16 + lm][kb];

        #pragma unroll
        for (int i = 0; i < 4; ++i)
            #pragma unroll
            for (int j = 0; j < 4; ++j)
                acc[i][j] = __builtin_amdgcn_mfma_f32_16x16x32_bf16(
                    af[i], bf[j], acc[i][j], 0, 0, 0);
        __syncthreads();
    }

    // C/D layout (m89-verified): col = lane&15, row = quad*4 + reg
    #pragma unroll
    for (int i = 0; i < 4; ++i)
        #pragma unroll
        for (int j = 0; j < 4; ++j) {
            const int col = bn + wcol + j * 16 + lm;
            #pragma unroll
            for (int r = 0; r < 4; ++r) {
                const int row = bm + wrow + i * 16 + quad * 4 + r;
                C[(size_t)row * ldc + col] = acc[i][j][r];
            }
        }
}

// ---------------- transpose + cast: out[cols][rows] bf16 = in[rows][cols] ---
__global__ __launch_bounds__(256) void transpose_cast(
    const float* __restrict__ in, unsigned short* __restrict__ out,
    int rows, int cols)
{
    __shared__ float tile[32][33];
    const int j0 = blockIdx.x * 32, i0 = blockIdx.y * 32;
    const int tx = threadIdx.x & 31, ty = threadIdx.x >> 5;  // ty 0..7
    #pragma unroll
    for (int k = 0; k < 4; ++k)
        tile[ty + 8 * k][tx] = in[(size_t)(i0 + ty + 8 * k) * cols + j0 + tx];
    __syncthreads();
    #pragma unroll
    for (int k = 0; k < 4; ++k)
        out[(size_t)(j0 + ty + 8 * k) * rows + i0 + tx] = f2bf(tile[tx][ty + 8 * k]);
}

// ---------------- straight cast f32 -> bf16 (4 elems/thread) ----------------
__global__ __launch_bounds__(256) void cast_bf16(
    const float* __restrict__ in, unsigned short* __restrict__ out)
{
    int i = (blockIdx.x * 256 + threadIdx.x) * 4;
    float4 v = *(const float4*)&in[i];
    ushort4 o;
    o.x = f2bf(v.x); o.y = f2bf(v.y); o.z = f2bf(v.z); o.w = f2bf(v.w);
    *(ushort4*)&out[i] = o;
}

// ---------------- fp32 tiled GEMM (kept for the two small GEMMs) ------------
#define BM 64
#define BN 64
#define BK 16
__global__ __launch_bounds__(256) void gemm_f32(
    const float* __restrict__ A, const float* __restrict__ B,
    float* __restrict__ C, int M, int N, int K,
    int lda, int ldb, int ldc, int mode, const float* __restrict__ bias)
{
    __shared__ __align__(16) float As[BK][BM];
    __shared__ __align__(16) float Bs[BK][BN];

    const int tid = threadIdx.x;
    const int bm = blockIdx.y * BM;
    const int bn = blockIdx.x * BN;

    const int am = tid >> 2;
    const int ak = (tid & 3) << 2;
    const int bk = tid >> 4;
    const int bnn = (tid & 15) << 2;

    const int tx = tid & 15, ty = tid >> 4;
    const int rm = ty << 2;
    const int rn = tx << 2;
    const int cm = bm + rm, cn = bn + rn;

    float acc[4][4] = {};

    for (int k0 = 0; k0 < K; k0 += BK) {
        const float* ap = A + (size_t)(bm + am) * lda + (k0 + ak);
        float4 av = *(const float4*)ap;
        As[ak + 0][am] = av.x;
        As[ak + 1][am] = av.y;
        As[ak + 2][am] = av.z;
        As[ak + 3][am] = av.w;
        {
            const int ncol = bn + bnn;
            const float* bp = B + (size_t)(k0 + bk) * ldb + ncol;
            float4 bv;
            if (ncol + 3 < N) {
                bv = *(const float4*)bp;
            } else {
                bv.x = (ncol + 0 < N) ? bp[0] : 0.f;
                bv.y = (ncol + 1 < N) ? bp[1] : 0.f;
                bv.z = (ncol + 2 < N) ? bp[2] : 0.f;
                bv.w = (ncol + 3 < N) ? bp[3] : 0.f;
            }
            *(float4*)&Bs[bk][bnn] = bv;
        }
        __syncthreads();

        #pragma unroll
        for (int k = 0; k < BK; ++k) {
            float4 a = *(const float4*)&As[k][rm];
            float4 b = *(const float4*)&Bs[k][rn];
            acc[0][0] += a.x * b.x; acc[0][1] += a.x * b.y;
            acc[0][2] += a.x * b.z; acc[0][3] += a.x * b.w;
            acc[1][0] += a.y * b.x; acc[1][1] += a.y * b.y;
            acc[1][2] += a.y * b.z; acc[1][3] += a.y * b.w;
            acc[2][0] += a.z * b.x; acc[2][1] += a.z * b.y;
            acc[2][2] += a.z * b.z; acc[2][3] += a.z * b.w;
            acc[3][0] += a.w * b.x; acc[3][1] += a.w * b.y;
            acc[3][2] += a.w * b.z; acc[3][3] += a.w * b.w;
        }
        __syncthreads();
    }

    #pragma unroll
    for (int i = 0; i < 4; ++i) {
        float* crow = C + (size_t)(cm + i) * ldc;
        #pragma unroll
        for (int j = 0; j < 4; ++j) {
            int col = cn + j;
            if (col < N) {
                float v = acc[i][j];
                if (mode == 1) {
                    v += bias[col];
                    v = (v > 20.f) ? v : logf(1.f + expf(v));  // softplus
                }
                crow[col] = v;
            }
        }
    }
}

// ---------------- depthwise causal conv(4) + bias + SiLU --------------------
__global__ __launch_bounds__(256) void conv_silu_kernel(
    const float* __restrict__ xz, const float* __restrict__ cw,
    const float* __restrict__ cb, float* __restrict__ uc)
{
    int idx = blockIdx.x * 256 + threadIdx.x;   // idx = r*2048 + d
    int d = idx & 2047;
    int r = idx >> 11;
    int l = r & 1023;

    float4 w4 = *(const float4*)(cw + 4 * d);
    float w[4] = { w4.x, w4.y, w4.z, w4.w };
    float acc = cb[d];
    const float* up = xz + (size_t)r * 4096 + d;
    if (l >= 3) {
        acc += w[0] * up[-3 * 4096] + w[1] * up[-2 * 4096]
             + w[2] * up[-1 * 4096] + w[3] * up[0];
    } else {
        #pragma unroll
        for (int j = 0; j < 4; ++j) {
            int lj = l - 3 + j;
            if (lj >= 0) acc += w[j] * up[(j - 3) * 4096];
        }
    }
    float sig = 1.f / (1.f + expf(-acc));
    uc[idx] = acc * sig;
}

// ---------------- selective scan (state-parallel) + fused epilogue ----------
// y = (scan_y + u*D) * silu(z)  ->  written as bf16 to yb (GEMM6's A operand)
#define SCB_CH 16
#define SCB_T  64
__global__ __launch_bounds__(256) void scan_kernel2(
    const float* __restrict__ uc,           // [2048][2048]
    const float* __restrict__ dtb,          // [2048][2048] dt
    const float* __restrict__ xz,           // z at [r][2048+d], stride 4096
    const float* __restrict__ xdbl,         // [2048][96], B@64, C@80
    const float* __restrict__ A_log,        // [2048][16]
    const float* __restrict__ Dvec,         // [2048]
    unsigned short* __restrict__ yb)        // [2048][2048] bf16 out
{
    __shared__ __align__(16) float s_u [SCB_T][SCB_CH];
    __shared__ __align__(16) float s_dt[SCB_T][SCB_CH];
    __shared__ __align__(16) float s_z [SCB_T][SCB_CH];
    __shared__ __align__(16) float s_bc[SCB_T][32];
    __shared__ __align__(16) float s_y [SCB_T][SCB_CH];

    const int tid  = threadIdx.x;
    const int wave = tid >> 6;
    const int lane = tid & 63;
    const int cg   = lane >> 4;
    const int n    = lane & 15;
    const int ch   = wave * 4 + cg;
    const int bb   = blockIdx.x >> 7;
    const int dbase = (blockIdx.x & 127) * SCB_CH;
    const int d    = dbase + ch;

    const float A2 = -expf(A_log[d * 16 + n]) * 1.44269504f;
    const float Dd = Dvec[d];

    float h = 0.f;
    const size_t rowbase = (size_t)bb * 1024;

    for (int t0 = 0; t0 < 1024; t0 += SCB_T) {
        for (int i = tid; i < SCB_T * 4; i += 256) {
            int tt = i >> 2; int cc = (i & 3) << 2;
            size_t r = rowbase + t0 + tt;
            *(float4*)&s_u [tt][cc] = *(const float4*)&uc [r * 2048 + dbase + cc];
            *(float4*)&s_dt[tt][cc] = *(const float4*)&dtb[r * 2048 + dbase + cc];
            *(float4*)&s_z [tt][cc] = *(const float4*)&xz [r * 4096 + 2048 + dbase + cc];
        }
        for (int i = tid; i < SCB_T * 8; i += 256) {
            int tt = i >> 3; int cc = (i & 7) << 2;
            size_t r = rowbase + t0 + tt;
            *(float4*)&s_bc[tt][cc] = *(const float4*)&xdbl[r * 96 + 64 + cc];
        }
        __syncthreads();

        #pragma unroll 4
        for (int t = 0; t < SCB_T; ++t) {
            float dtv = s_dt[t][ch];
            float uv  = s_u[t][ch];
            float dA  = exp2f(dtv * A2);
            float bn  = s_bc[t][n];
            float cn  = s_bc[t][16 + n];
            h = dA * h + (dtv * uv) * bn;
            float p = h * cn;
            p += __shfl_xor(p, 1);
            p += __shfl_xor(p, 2);
            p += __shfl_xor(p, 4);
            p += __shfl_xor(p, 8);
            if (n == 0) {
                float zv = s_z[t][ch];
                float yv = p + uv * Dd;
                yv *= zv / (1.f + expf(-zv));
                s_y[t][ch] = yv;
            }
        }
        __syncthreads();

        for (int i = tid; i < SCB_T * 4; i += 256) {
            int tt = i >> 2; int cc = (i & 3) << 2;
            size_t r = rowbase + t0 + tt;
            float4 v = *(const float4*)&s_y[tt][cc];
            ushort4 o;
            o.x = f2bf(v.x); o.y = f2bf(v.y); o.z = f2bf(v.z); o.w = f2bf(v.w);
            *(ushort4*)&yb[r * 2048 + dbase + cc] = o;
        }
        __syncthreads();
    }
}

extern "C" void kernel_launch(void* const* d_in, const int* in_sizes, int n_in,
                              void* d_out, int out_size, void* d_ws, size_t ws_size,
                              hipStream_t stream)
{
    const float* x      = (const float*)d_in[0];
    const float* W_in   = (const float*)d_in[1];
    const float* conv_w = (const float*)d_in[2];
    const float* conv_b = (const float*)d_in[3];
    const float* W_x    = (const float*)d_in[4];
    const float* W_dt   = (const float*)d_in[5];
    const float* b_dt   = (const float*)d_in[6];
    const float* A_log  = (const float*)d_in[7];
    const float* Dv     = (const float*)d_in[8];
    const float* W_out  = (const float*)d_in[9];
    float* out = (float*)d_out;

    float* ws   = (float*)d_ws;
    float* xz   = ws;                        // [2048][4096] f32
    float* uc   = xz + 8388608;              // [2048][2048] f32
    float* xdbl = uc + 4194304;              // [2048][96]   f32
    float* dtb  = xdbl + 196608;             // [2048][2048] f32
    unsigned short* bfbase = (unsigned short*)(dtb + 4194304);
    unsigned short* xb   = bfbase;           // [2048][1024] bf16
    unsigned short* wbT  = xb + 2097152;     // [4096][1024] bf16 (W_in^T)
    unsigned short* wobT = wbT + 4194304;    // [1024][2048] bf16 (W_out^T)
    unsigned short* yb   = wbT;              // [2048][2048] bf16 — aliases wbT
                                             // (wbT dead after GEMM1)
    dim3 blk(256);

    // prep: casts / transposes
    transpose_cast<<<dim3(128, 32), blk, 0, stream>>>(W_in, wbT, 1024, 4096);
    transpose_cast<<<dim3(32, 64), blk, 0, stream>>>(W_out, wobT, 2048, 1024);
    cast_bf16<<<2048, blk, 0, stream>>>(x, xb);

    // 1. xz = x @ W_in          (bf16 MFMA)
    gemm_bf16<<<dim3(32, 16), blk, 0, stream>>>(xb, wbT, xz, 1024, 1024, 1024, 4096);

    // 2. u_c = silu(conv(u) + cb)
    conv_silu_kernel<<<(2048 * 2048) / 256, blk, 0, stream>>>(xz, conv_w, conv_b, uc);

    // 3. x_dbl = u_c @ W_x      (fp32)
    gemm_f32<<<dim3(2, 32), blk, 0, stream>>>(
        uc, W_x, xdbl, 2048, 96, 2048, 2048, 96, 96, 0, nullptr);

    // 4. dt = softplus(x_dbl[:, :64] @ W_dt + b_dt)   (fp32)
    gemm_f32<<<dim3(32, 32), blk, 0, stream>>>(
        xdbl, W_dt, dtb, 2048, 2048, 64, 96, 2048, 2048, 1, b_dt);

    // 5. selective scan + epilogue -> yb (bf16)
    scan_kernel2<<<256, blk, 0, stream>>>(uc, dtb, xz, xdbl, A_log, Dv, yb);

    // 6. out = y @ W_out        (bf16 MFMA)
    gemm_bf16<<<dim3(8, 16), blk, 0, stream>>>(yb, wobT, out, 2048, 2048, 2048, 1024);
}

// Round 4
// 443.063 us; speedup vs baseline: 2.6878x; 1.4443x over previous
//
#include <hip/hip_runtime.h>
#include <hip/hip_bf16.h>

// ---------------------------------------------------------------------------
// Mamba block forward. Round 4: chunk-parallel selective scan (3 passes) +
// 64-row-tile bf16 GEMM for y@W_out. B=2 L=1024 DM=1024 DI=2048 DS=16 DTR=64
// ---------------------------------------------------------------------------

typedef __attribute__((ext_vector_type(8))) short bfrag;
typedef __attribute__((ext_vector_type(4))) float f32x4;

#define CF  8     // scan time-chunks
#define CL  128   // steps per chunk
#define SCT 64    // LDS window within a chunk

__device__ __forceinline__ unsigned short f2bf(float f) {
    unsigned int u = __float_as_uint(f);
    u += 0x7FFF + ((u >> 16) & 1);          // round-to-nearest-even
    return (unsigned short)(u >> 16);
}

// ---------------- bf16 MFMA GEMM: C[M][N] = A[M][K] * BT[N][K]^T ------------
// Block tile MT x 128, 4 waves. MT=128: wave 64x64 (4x4 frags).
// MT=64: waves side-by-side, wave 64x32 (4x2 frags).
template<int MT>
__global__ __launch_bounds__(256) void gemm_bf16(
    const unsigned short* __restrict__ A,   // [M][K] bf16
    const unsigned short* __restrict__ BT,  // [N][K] bf16
    float* __restrict__ C,                  // [M][N] fp32
    int K, int lda, int ldb, int ldc)
{
    constexpr int FJ = (MT == 128) ? 4 : 2;
    __shared__ unsigned short sA[MT][40];
    __shared__ unsigned short sB[128][40];

    const int tid  = threadIdx.x;
    const int wave = tid >> 6, lane = tid & 63;
    const int lm   = lane & 15;
    const int quad = lane >> 4;
    const int kb   = quad << 3;
    const int wrow = (MT == 128) ? ((wave >> 1) << 6) : 0;
    const int wcol = (MT == 128) ? ((wave & 1) << 6) : (wave << 5);
    const int bm = blockIdx.y * MT, bn = blockIdx.x * 128;

    const int srow = tid >> 2;
    const int scol = (tid & 3) << 3;

    f32x4 acc[4][FJ];
    #pragma unroll
    for (int i = 0; i < 4; ++i)
        #pragma unroll
        for (int j = 0; j < FJ; ++j) {
            acc[i][j][0] = 0.f; acc[i][j][1] = 0.f;
            acc[i][j][2] = 0.f; acc[i][j][3] = 0.f;
        }

    for (int k0 = 0; k0 < K; k0 += 32) {
        *(float4*)&sA[srow][scol] = *(const float4*)&A[(size_t)(bm + srow) * lda + k0 + scol];
        if (MT == 128)
            *(float4*)&sA[srow + 64][scol] = *(const float4*)&A[(size_t)(bm + srow + 64) * lda + k0 + scol];
        *(float4*)&sB[srow][scol]      = *(const float4*)&BT[(size_t)(bn + srow)      * ldb + k0 + scol];
        *(float4*)&sB[srow + 64][scol] = *(const float4*)&BT[(size_t)(bn + srow + 64) * ldb + k0 + scol];
        __syncthreads();

        bfrag af[4], bf[FJ];
        #pragma unroll
        for (int i = 0; i < 4; ++i) af[i] = *(const bfrag*)&sA[wrow + i * 16 + lm][kb];
        #pragma unroll
        for (int j = 0; j < FJ; ++j) bf[j] = *(const bfrag*)&sB[wcol + j * 16 + lm][kb];

        #pragma unroll
        for (int i = 0; i < 4; ++i)
            #pragma unroll
            for (int j = 0; j < FJ; ++j)
                acc[i][j] = __builtin_amdgcn_mfma_f32_16x16x32_bf16(
                    af[i], bf[j], acc[i][j], 0, 0, 0);
        __syncthreads();
    }

    // C/D layout: col = lane&15, row = quad*4 + reg
    #pragma unroll
    for (int i = 0; i < 4; ++i)
        #pragma unroll
        for (int j = 0; j < FJ; ++j) {
            const int col = bn + wcol + j * 16 + lm;
            #pragma unroll
            for (int r = 0; r < 4; ++r) {
                const int row = bm + wrow + i * 16 + quad * 4 + r;
                C[(size_t)row * ldc + col] = acc[i][j][r];
            }
        }
}

// ---------------- transpose + cast: out[cols][rows] bf16 = in[rows][cols] ---
__global__ __launch_bounds__(256) void transpose_cast(
    const float* __restrict__ in, unsigned short* __restrict__ out,
    int rows, int cols)
{
    __shared__ float tile[32][33];
    const int j0 = blockIdx.x * 32, i0 = blockIdx.y * 32;
    const int tx = threadIdx.x & 31, ty = threadIdx.x >> 5;
    #pragma unroll
    for (int k = 0; k < 4; ++k)
        tile[ty + 8 * k][tx] = in[(size_t)(i0 + ty + 8 * k) * cols + j0 + tx];
    __syncthreads();
    #pragma unroll
    for (int k = 0; k < 4; ++k)
        out[(size_t)(j0 + ty + 8 * k) * rows + i0 + tx] = f2bf(tile[tx][ty + 8 * k]);
}

__global__ __launch_bounds__(256) void cast_bf16(
    const float* __restrict__ in, unsigned short* __restrict__ out)
{
    int i = (blockIdx.x * 256 + threadIdx.x) * 4;
    float4 v = *(const float4*)&in[i];
    ushort4 o;
    o.x = f2bf(v.x); o.y = f2bf(v.y); o.z = f2bf(v.z); o.w = f2bf(v.w);
    *(ushort4*)&out[i] = o;
}

// ---------------- fp32 tiled GEMM (two small GEMMs) -------------------------
#define BM 64
#define BN 64
#define BK 16
__global__ __launch_bounds__(256) void gemm_f32(
    const float* __restrict__ A, const float* __restrict__ B,
    float* __restrict__ C, int M, int N, int K,
    int lda, int ldb, int ldc, int mode, const float* __restrict__ bias)
{
    __shared__ __align__(16) float As[BK][BM];
    __shared__ __align__(16) float Bs[BK][BN];

    const int tid = threadIdx.x;
    const int bm = blockIdx.y * BM;
    const int bn = blockIdx.x * BN;

    const int am = tid >> 2;
    const int ak = (tid & 3) << 2;
    const int bk = tid >> 4;
    const int bnn = (tid & 15) << 2;

    const int tx = tid & 15, ty = tid >> 4;
    const int rm = ty << 2;
    const int rn = tx << 2;
    const int cm = bm + rm, cn = bn + rn;

    float acc[4][4] = {};

    for (int k0 = 0; k0 < K; k0 += BK) {
        const float* ap = A + (size_t)(bm + am) * lda + (k0 + ak);
        float4 av = *(const float4*)ap;
        As[ak + 0][am] = av.x;
        As[ak + 1][am] = av.y;
        As[ak + 2][am] = av.z;
        As[ak + 3][am] = av.w;
        {
            const int ncol = bn + bnn;
            const float* bp = B + (size_t)(k0 + bk) * ldb + ncol;
            float4 bv;
            if (ncol + 3 < N) {
                bv = *(const float4*)bp;
            } else {
                bv.x = (ncol + 0 < N) ? bp[0] : 0.f;
                bv.y = (ncol + 1 < N) ? bp[1] : 0.f;
                bv.z = (ncol + 2 < N) ? bp[2] : 0.f;
                bv.w = (ncol + 3 < N) ? bp[3] : 0.f;
            }
            *(float4*)&Bs[bk][bnn] = bv;
        }
        __syncthreads();

        #pragma unroll
        for (int k = 0; k < BK; ++k) {
            float4 a = *(const float4*)&As[k][rm];
            float4 b = *(const float4*)&Bs[k][rn];
            acc[0][0] += a.x * b.x; acc[0][1] += a.x * b.y;
            acc[0][2] += a.x * b.z; acc[0][3] += a.x * b.w;
            acc[1][0] += a.y * b.x; acc[1][1] += a.y * b.y;
            acc[1][2] += a.y * b.z; acc[1][3] += a.y * b.w;
            acc[2][0] += a.z * b.x; acc[2][1] += a.z * b.y;
            acc[2][2] += a.z * b.z; acc[2][3] += a.z * b.w;
            acc[3][0] += a.w * b.x; acc[3][1] += a.w * b.y;
            acc[3][2] += a.w * b.z; acc[3][3] += a.w * b.w;
        }
        __syncthreads();
    }

    #pragma unroll
    for (int i = 0; i < 4; ++i) {
        float* crow = C + (size_t)(cm + i) * ldc;
        #pragma unroll
        for (int j = 0; j < 4; ++j) {
            int col = cn + j;
            if (col < N) {
                float v = acc[i][j];
                if (mode == 1) {
                    v += bias[col];
                    v = (v > 20.f) ? v : logf(1.f + expf(v));  // softplus
                }
                crow[col] = v;
            }
        }
    }
}

// ---------------- depthwise causal conv(4) + bias + SiLU --------------------
__global__ __launch_bounds__(256) void conv_silu_kernel(
    const float* __restrict__ xz, const float* __restrict__ cw,
    const float* __restrict__ cb, float* __restrict__ uc)
{
    int idx = blockIdx.x * 256 + threadIdx.x;
    int d = idx & 2047;
    int r = idx >> 11;
    int l = r & 1023;

    float4 w4 = *(const float4*)(cw + 4 * d);
    float w[4] = { w4.x, w4.y, w4.z, w4.w };
    float acc = cb[d];
    const float* up = xz + (size_t)r * 4096 + d;
    if (l >= 3) {
        acc += w[0] * up[-3 * 4096] + w[1] * up[-2 * 4096]
             + w[2] * up[-1 * 4096] + w[3] * up[0];
    } else {
        #pragma unroll
        for (int j = 0; j < 4; ++j) {
            int lj = l - 3 + j;
            if (lj >= 0) acc += w[j] * up[(j - 3) * 4096];
        }
    }
    float sig = 1.f / (1.f + expf(-acc));
    uc[idx] = acc * sig;
}

// ---------------------------------------------------------------------------
// Chunk-parallel selective scan.
// Block = 16 channels x 16 states (4 waves of 4ch x 16n).
// Grid = 2 batches x 128 ch-groups x CF chunks = 2048 blocks.
// blockIdx.x = b*1024 + dg*CF + chunk
// ---------------------------------------------------------------------------

// Pass 1: per-chunk local scan from h=0; emit P = prod(dA), Hend.
__global__ __launch_bounds__(256) void scan_pass1(
    const float* __restrict__ uc,     // [2048][2048]
    const float* __restrict__ dtb,    // [2048][2048]
    const float* __restrict__ xdbl,   // [2048][96], B@64
    const float* __restrict__ A_log,  // [2048][16]
    float* __restrict__ Pout,         // [2][CF][2048][16]
    float* __restrict__ Hend)         // [2][CF][2048][16]
{
    __shared__ __align__(16) float s_u [SCT][16];
    __shared__ __align__(16) float s_dt[SCT][16];
    __shared__ __align__(16) float s_b [SCT][16];

    const int tid  = threadIdx.x;
    const int wave = tid >> 6, lane = tid & 63;
    const int ch   = wave * 4 + (lane >> 4);
    const int n    = lane & 15;
    const int bx   = blockIdx.x;
    const int b    = bx >> 10;
    const int dg   = (bx >> 3) & 127;
    const int chunk = bx & 7;
    const int dbase = dg * 16;
    const int d    = dbase + ch;

    const float A2 = -expf(A_log[d * 16 + n]) * 1.44269504f;

    float h = 0.f, Pp = 1.f;
    const size_t rowbase = (size_t)b * 1024 + chunk * CL;

    for (int w = 0; w < CL; w += SCT) {
        for (int i = tid; i < SCT * 4; i += 256) {
            int tt = i >> 2; int cc = (i & 3) << 2;
            size_t r = rowbase + w + tt;
            *(float4*)&s_u [tt][cc] = *(const float4*)&uc [r * 2048 + dbase + cc];
            *(float4*)&s_dt[tt][cc] = *(const float4*)&dtb[r * 2048 + dbase + cc];
            *(float4*)&s_b [tt][cc] = *(const float4*)&xdbl[r * 96 + 64 + cc];
        }
        __syncthreads();
        #pragma unroll 8
        for (int t = 0; t < SCT; ++t) {
            float dtv = s_dt[t][ch];
            float uv  = s_u[t][ch];
            float dA  = exp2f(dtv * A2);
            h = dA * h + (dtv * uv) * s_b[t][n];
            Pp *= dA;
        }
        __syncthreads();
    }
    size_t idx = (((size_t)(b * CF + chunk) * 2048) + d) * 16 + n;
    Pout[idx] = Pp;
    Hend[idx] = h;
}

// Pass 2: serial combine over CF chunks -> per-chunk entry state Hin.
__global__ __launch_bounds__(256) void scan_pass2(
    const float* __restrict__ P, const float* __restrict__ Hend,
    float* __restrict__ Hin)
{
    int gid = blockIdx.x * 256 + threadIdx.x;   // 0..65535
    int b = gid >> 15;
    int rest = gid & 32767;                     // (d,n)
    float H = 0.f;
    #pragma unroll
    for (int c = 0; c < CF; ++c) {
        size_t idx = ((size_t)(b * CF + c) << 15) + rest;
        Hin[idx] = H;
        H = P[idx] * H + Hend[idx];
    }
}

// Pass 3: replay each chunk from Hin, fused epilogue, y -> bf16.
__global__ __launch_bounds__(256) void scan_pass3(
    const float* __restrict__ uc,
    const float* __restrict__ dtb,
    const float* __restrict__ xz,     // z at [r][2048+d], stride 4096
    const float* __restrict__ xdbl,   // B@64, C@80
    const float* __restrict__ A_log,
    const float* __restrict__ Dvec,
    const float* __restrict__ Hin,
    unsigned short* __restrict__ yb)  // [2048][2048] bf16
{
    __shared__ __align__(16) float s_u [SCT][16];
    __shared__ __align__(16) float s_dt[SCT][16];
    __shared__ __align__(16) float s_z [SCT][16];
    __shared__ __align__(16) float s_bc[SCT][32];
    __shared__ __align__(16) float s_y [SCT][16];

    const int tid  = threadIdx.x;
    const int wave = tid >> 6, lane = tid & 63;
    const int ch   = wave * 4 + (lane >> 4);
    const int n    = lane & 15;
    const int bx   = blockIdx.x;
    const int b    = bx >> 10;
    const int dg   = (bx >> 3) & 127;
    const int chunk = bx & 7;
    const int dbase = dg * 16;
    const int d    = dbase + ch;

    const float A2 = -expf(A_log[d * 16 + n]) * 1.44269504f;
    const float Dd = Dvec[d];

    float h = Hin[(((size_t)(b * CF + chunk) * 2048) + d) * 16 + n];
    const size_t rowbase = (size_t)b * 1024 + chunk * CL;

    for (int w = 0; w < CL; w += SCT) {
        for (int i = tid; i < SCT * 4; i += 256) {
            int tt = i >> 2; int cc = (i & 3) << 2;
            size_t r = rowbase + w + tt;
            *(float4*)&s_u [tt][cc] = *(const float4*)&uc [r * 2048 + dbase + cc];
            *(float4*)&s_dt[tt][cc] = *(const float4*)&dtb[r * 2048 + dbase + cc];
            *(float4*)&s_z [tt][cc] = *(const float4*)&xz [r * 4096 + 2048 + dbase + cc];
        }
        for (int i = tid; i < SCT * 8; i += 256) {
            int tt = i >> 3; int cc = (i & 7) << 2;
            size_t r = rowbase + w + tt;
            *(float4*)&s_bc[tt][cc] = *(const float4*)&xdbl[r * 96 + 64 + cc];
        }
        __syncthreads();

        #pragma unroll 4
        for (int t = 0; t < SCT; ++t) {
            float dtv = s_dt[t][ch];
            float uv  = s_u[t][ch];
            float dA  = exp2f(dtv * A2);
            float bn  = s_bc[t][n];
            float cn  = s_bc[t][16 + n];
            h = dA * h + (dtv * uv) * bn;
            float p = h * cn;
            p += __shfl_xor(p, 1);
            p += __shfl_xor(p, 2);
            p += __shfl_xor(p, 4);
            p += __shfl_xor(p, 8);
            if (n == 0) {
                float zv = s_z[t][ch];
                float yv = p + uv * Dd;
                yv *= zv / (1.f + expf(-zv));
                s_y[t][ch] = yv;
            }
        }
        __syncthreads();

        for (int i = tid; i < SCT * 4; i += 256) {
            int tt = i >> 2; int cc = (i & 3) << 2;
            size_t r = rowbase + w + tt;
            float4 v = *(const float4*)&s_y[tt][cc];
            ushort4 o;
            o.x = f2bf(v.x); o.y = f2bf(v.y); o.z = f2bf(v.z); o.w = f2bf(v.w);
            *(ushort4*)&yb[r * 2048 + dbase + cc] = o;
        }
        __syncthreads();
    }
}

extern "C" void kernel_launch(void* const* d_in, const int* in_sizes, int n_in,
                              void* d_out, int out_size, void* d_ws, size_t ws_size,
                              hipStream_t stream)
{
    const float* x      = (const float*)d_in[0];
    const float* W_in   = (const float*)d_in[1];
    const float* conv_w = (const float*)d_in[2];
    const float* conv_b = (const float*)d_in[3];
    const float* W_x    = (const float*)d_in[4];
    const float* W_dt   = (const float*)d_in[5];
    const float* b_dt   = (const float*)d_in[6];
    const float* A_log  = (const float*)d_in[7];
    const float* Dv     = (const float*)d_in[8];
    const float* W_out  = (const float*)d_in[9];
    float* out = (float*)d_out;

    float* ws   = (float*)d_ws;
    float* xz   = ws;                        // [2048][4096] f32
    float* uc   = xz + 8388608;              // [2048][2048] f32
    float* xdbl = uc + 4194304;              // [2048][96]   f32
    float* dtb  = xdbl + 196608;             // [2048][2048] f32
    float* Hend = dtb + 4194304;             // [2][CF][2048][16] = 524288
    float* Hin  = Hend + 524288;             // 524288
    unsigned short* bfbase = (unsigned short*)(Hin + 524288);
    unsigned short* xb   = bfbase;           // [2048][1024] bf16 (4 MB)
    unsigned short* wbT  = xb + 2097152;     // [4096][1024] bf16 (W_in^T)
    unsigned short* wobT = wbT + 4194304;    // [1024][2048] bf16 (W_out^T)
    unsigned short* yb   = wbT;              // aliases wbT (dead after GEMM1)
    float* Pbuf = (float*)xb;                // aliases xb (dead after GEMM1), 2 MB

    dim3 blk(256);

    // prep
    transpose_cast<<<dim3(128, 32), blk, 0, stream>>>(W_in, wbT, 1024, 4096);
    transpose_cast<<<dim3(32, 64), blk, 0, stream>>>(W_out, wobT, 2048, 1024);
    cast_bf16<<<2048, blk, 0, stream>>>(x, xb);

    // 1. xz = x @ W_in          (bf16 MFMA, 512 blocks)
    gemm_bf16<128><<<dim3(32, 16), blk, 0, stream>>>(xb, wbT, xz, 1024, 1024, 1024, 4096);

    // 2. u_c = silu(conv(u) + cb)
    conv_silu_kernel<<<(2048 * 2048) / 256, blk, 0, stream>>>(xz, conv_w, conv_b, uc);

    // 3. x_dbl = u_c @ W_x      (fp32)
    gemm_f32<<<dim3(2, 32), blk, 0, stream>>>(
        uc, W_x, xdbl, 2048, 96, 2048, 2048, 96, 96, 0, nullptr);

    // 4. dt = softplus(x_dbl[:, :64] @ W_dt + b_dt)   (fp32)
    gemm_f32<<<dim3(32, 32), blk, 0, stream>>>(
        xdbl, W_dt, dtb, 2048, 2048, 64, 96, 2048, 2048, 1, b_dt);

    // 5. chunk-parallel scan
    scan_pass1<<<2048, blk, 0, stream>>>(uc, dtb, xdbl, A_log, Pbuf, Hend);
    scan_pass2<<<256, blk, 0, stream>>>(Pbuf, Hend, Hin);
    scan_pass3<<<2048, blk, 0, stream>>>(uc, dtb, xz, xdbl, A_log, Dv, Hin, yb);

    // 6. out = y @ W_out        (bf16 MFMA, 256 blocks)
    gemm_bf16<64><<<dim3(8, 32), blk, 0, stream>>>(yb, wobT, out, 2048, 2048, 2048, 1024);
}

// Round 5
// 401.571 us; speedup vs baseline: 2.9655x; 1.1033x over previous
//
#include <hip/hip_runtime.h>
#include <hip/hip_bf16.h>

// ---------------------------------------------------------------------------
// Mamba block forward. Round 5: split-K fp32 GEMM for x_dbl = u_c @ W_x
// (was 64 blocks / 0.25 per CU -> 512 blocks + atomicAdd reduction).
// B=2 L=1024 DM=1024 DI=2048 DS=16 DTR=64
// ---------------------------------------------------------------------------

typedef __attribute__((ext_vector_type(8))) short bfrag;
typedef __attribute__((ext_vector_type(4))) float f32x4;

#define CF  8     // scan time-chunks
#define CL  128   // steps per chunk
#define SCT 64    // LDS window within a chunk

__device__ __forceinline__ unsigned short f2bf(float f) {
    unsigned int u = __float_as_uint(f);
    u += 0x7FFF + ((u >> 16) & 1);          // round-to-nearest-even
    return (unsigned short)(u >> 16);
}

// ---------------- bf16 MFMA GEMM: C[M][N] = A[M][K] * BT[N][K]^T ------------
template<int MT>
__global__ __launch_bounds__(256) void gemm_bf16(
    const unsigned short* __restrict__ A,   // [M][K] bf16
    const unsigned short* __restrict__ BT,  // [N][K] bf16
    float* __restrict__ C,                  // [M][N] fp32
    int K, int lda, int ldb, int ldc)
{
    constexpr int FJ = (MT == 128) ? 4 : 2;
    __shared__ unsigned short sA[MT][40];
    __shared__ unsigned short sB[128][40];

    const int tid  = threadIdx.x;
    const int wave = tid >> 6, lane = tid & 63;
    const int lm   = lane & 15;
    const int quad = lane >> 4;
    const int kb   = quad << 3;
    const int wrow = (MT == 128) ? ((wave >> 1) << 6) : 0;
    const int wcol = (MT == 128) ? ((wave & 1) << 6) : (wave << 5);
    const int bm = blockIdx.y * MT, bn = blockIdx.x * 128;

    const int srow = tid >> 2;
    const int scol = (tid & 3) << 3;

    f32x4 acc[4][FJ];
    #pragma unroll
    for (int i = 0; i < 4; ++i)
        #pragma unroll
        for (int j = 0; j < FJ; ++j) {
            acc[i][j][0] = 0.f; acc[i][j][1] = 0.f;
            acc[i][j][2] = 0.f; acc[i][j][3] = 0.f;
        }

    for (int k0 = 0; k0 < K; k0 += 32) {
        *(float4*)&sA[srow][scol] = *(const float4*)&A[(size_t)(bm + srow) * lda + k0 + scol];
        if (MT == 128)
            *(float4*)&sA[srow + 64][scol] = *(const float4*)&A[(size_t)(bm + srow + 64) * lda + k0 + scol];
        *(float4*)&sB[srow][scol]      = *(const float4*)&BT[(size_t)(bn + srow)      * ldb + k0 + scol];
        *(float4*)&sB[srow + 64][scol] = *(const float4*)&BT[(size_t)(bn + srow + 64) * ldb + k0 + scol];
        __syncthreads();

        bfrag af[4], bf[FJ];
        #pragma unroll
        for (int i = 0; i < 4; ++i) af[i] = *(const bfrag*)&sA[wrow + i * 16 + lm][kb];
        #pragma unroll
        for (int j = 0; j < FJ; ++j) bf[j] = *(const bfrag*)&sB[wcol + j * 16 + lm][kb];

        #pragma unroll
        for (int i = 0; i < 4; ++i)
            #pragma unroll
            for (int j = 0; j < FJ; ++j)
                acc[i][j] = __builtin_amdgcn_mfma_f32_16x16x32_bf16(
                    af[i], bf[j], acc[i][j], 0, 0, 0);
        __syncthreads();
    }

    // C/D layout: col = lane&15, row = quad*4 + reg
    #pragma unroll
    for (int i = 0; i < 4; ++i)
        #pragma unroll
        for (int j = 0; j < FJ; ++j) {
            const int col = bn + wcol + j * 16 + lm;
            #pragma unroll
            for (int r = 0; r < 4; ++r) {
                const int row = bm + wrow + i * 16 + quad * 4 + r;
                C[(size_t)row * ldc + col] = acc[i][j][r];
            }
        }
}

// ---------------- transpose + cast ------------------------------------------
__global__ __launch_bounds__(256) void transpose_cast(
    const float* __restrict__ in, unsigned short* __restrict__ out,
    int rows, int cols)
{
    __shared__ float tile[32][33];
    const int j0 = blockIdx.x * 32, i0 = blockIdx.y * 32;
    const int tx = threadIdx.x & 31, ty = threadIdx.x >> 5;
    #pragma unroll
    for (int k = 0; k < 4; ++k)
        tile[ty + 8 * k][tx] = in[(size_t)(i0 + ty + 8 * k) * cols + j0 + tx];
    __syncthreads();
    #pragma unroll
    for (int k = 0; k < 4; ++k)
        out[(size_t)(j0 + ty + 8 * k) * rows + i0 + tx] = f2bf(tile[tx][ty + 8 * k]);
}

__global__ __launch_bounds__(256) void cast_bf16(
    const float* __restrict__ in, unsigned short* __restrict__ out)
{
    int i = (blockIdx.x * 256 + threadIdx.x) * 4;
    float4 v = *(const float4*)&in[i];
    ushort4 o;
    o.x = f2bf(v.x); o.y = f2bf(v.y); o.z = f2bf(v.z); o.w = f2bf(v.w);
    *(ushort4*)&out[i] = o;
}

__global__ __launch_bounds__(256) void zero_f32(float* __restrict__ p)
{
    int i = (blockIdx.x * 256 + threadIdx.x) * 4;
    *(float4*)&p[i] = float4{0.f, 0.f, 0.f, 0.f};
}

// ---------------- split-K fp32 GEMM for x_dbl = u_c @ W_x -------------------
// C[2048][96] += A[2048][2048] @ B[2048][96], K sliced 16 x 128.
// Grid = 32 m-tiles x 16 k-slices = 512 blocks. atomicAdd epilogue.
#define SK_KS 128
__global__ __launch_bounds__(256) void gemm_f32_splitk(
    const float* __restrict__ A, const float* __restrict__ B,
    float* __restrict__ C)
{
    __shared__ __align__(16) float As[16][64];
    __shared__ __align__(16) float Bs[16][96];

    const int tid = threadIdx.x;
    const int mtile = blockIdx.x >> 4;           // 0..31
    const int kslice = blockIdx.x & 15;          // 0..15
    const int bm = mtile * 64;
    const int kbase = kslice * SK_KS;

    const int am = tid >> 2;                     // 0..63
    const int ak = (tid & 3) << 2;               // 0,4,8,12

    const int ty = tid >> 4, tx = tid & 15;
    const int rm = ty << 2;                      // 0..60
    const int rn = tx * 6;                       // 0..90

    float acc[4][6] = {};

    for (int k0 = 0; k0 < SK_KS; k0 += 16) {
        // A tile 64x16: thread -> float4 along K, store transposed
        float4 av = *(const float4*)&A[(size_t)(bm + am) * 2048 + kbase + k0 + ak];
        As[ak + 0][am] = av.x;
        As[ak + 1][am] = av.y;
        As[ak + 2][am] = av.z;
        As[ak + 3][am] = av.w;
        // B tile 16x96 = 384 float4
        for (int i = tid; i < 384; i += 256) {
            int br = i / 24, bc = (i % 24) << 2;
            *(float4*)&Bs[br][bc] = *(const float4*)&B[(size_t)(kbase + k0 + br) * 96 + bc];
        }
        __syncthreads();

        #pragma unroll
        for (int k = 0; k < 16; ++k) {
            float4 a = *(const float4*)&As[k][rm];
            float b[6];
            #pragma unroll
            for (int j = 0; j < 6; ++j) b[j] = Bs[k][rn + j];
            #pragma unroll
            for (int j = 0; j < 6; ++j) {
                acc[0][j] += a.x * b[j];
                acc[1][j] += a.y * b[j];
                acc[2][j] += a.z * b[j];
                acc[3][j] += a.w * b[j];
            }
        }
        __syncthreads();
    }

    #pragma unroll
    for (int i = 0; i < 4; ++i) {
        float* crow = C + (size_t)(bm + rm + i) * 96 + rn;
        #pragma unroll
        for (int j = 0; j < 6; ++j)
            atomicAdd(&crow[j], acc[i][j]);
    }
}

// ---------------- fp32 tiled GEMM (dt GEMM) ---------------------------------
#define BM 64
#define BN 64
#define BK 16
__global__ __launch_bounds__(256) void gemm_f32(
    const float* __restrict__ A, const float* __restrict__ B,
    float* __restrict__ C, int M, int N, int K,
    int lda, int ldb, int ldc, int mode, const float* __restrict__ bias)
{
    __shared__ __align__(16) float As[BK][BM];
    __shared__ __align__(16) float Bs[BK][BN];

    const int tid = threadIdx.x;
    const int bm = blockIdx.y * BM;
    const int bn = blockIdx.x * BN;

    const int am = tid >> 2;
    const int ak = (tid & 3) << 2;
    const int bk = tid >> 4;
    const int bnn = (tid & 15) << 2;

    const int tx = tid & 15, ty = tid >> 4;
    const int rm = ty << 2;
    const int rn = tx << 2;
    const int cm = bm + rm, cn = bn + rn;

    float acc[4][4] = {};

    for (int k0 = 0; k0 < K; k0 += BK) {
        const float* ap = A + (size_t)(bm + am) * lda + (k0 + ak);
        float4 av = *(const float4*)ap;
        As[ak + 0][am] = av.x;
        As[ak + 1][am] = av.y;
        As[ak + 2][am] = av.z;
        As[ak + 3][am] = av.w;
        {
            const int ncol = bn + bnn;
            const float* bp = B + (size_t)(k0 + bk) * ldb + ncol;
            float4 bv;
            if (ncol + 3 < N) {
                bv = *(const float4*)bp;
            } else {
                bv.x = (ncol + 0 < N) ? bp[0] : 0.f;
                bv.y = (ncol + 1 < N) ? bp[1] : 0.f;
                bv.z = (ncol + 2 < N) ? bp[2] : 0.f;
                bv.w = (ncol + 3 < N) ? bp[3] : 0.f;
            }
            *(float4*)&Bs[bk][bnn] = bv;
        }
        __syncthreads();

        #pragma unroll
        for (int k = 0; k < BK; ++k) {
            float4 a = *(const float4*)&As[k][rm];
            float4 b = *(const float4*)&Bs[k][rn];
            acc[0][0] += a.x * b.x; acc[0][1] += a.x * b.y;
            acc[0][2] += a.x * b.z; acc[0][3] += a.x * b.w;
            acc[1][0] += a.y * b.x; acc[1][1] += a.y * b.y;
            acc[1][2] += a.y * b.z; acc[1][3] += a.y * b.w;
            acc[2][0] += a.z * b.x; acc[2][1] += a.z * b.y;
            acc[2][2] += a.z * b.z; acc[2][3] += a.z * b.w;
            acc[3][0] += a.w * b.x; acc[3][1] += a.w * b.y;
            acc[3][2] += a.w * b.z; acc[3][3] += a.w * b.w;
        }
        __syncthreads();
    }

    #pragma unroll
    for (int i = 0; i < 4; ++i) {
        float* crow = C + (size_t)(cm + i) * ldc;
        #pragma unroll
        for (int j = 0; j < 4; ++j) {
            int col = cn + j;
            if (col < N) {
                float v = acc[i][j];
                if (mode == 1) {
                    v += bias[col];
                    v = (v > 20.f) ? v : logf(1.f + expf(v));  // softplus
                }
                crow[col] = v;
            }
        }
    }
}

// ---------------- depthwise causal conv(4) + bias + SiLU --------------------
__global__ __launch_bounds__(256) void conv_silu_kernel(
    const float* __restrict__ xz, const float* __restrict__ cw,
    const float* __restrict__ cb, float* __restrict__ uc)
{
    int idx = blockIdx.x * 256 + threadIdx.x;
    int d = idx & 2047;
    int r = idx >> 11;
    int l = r & 1023;

    float4 w4 = *(const float4*)(cw + 4 * d);
    float w[4] = { w4.x, w4.y, w4.z, w4.w };
    float acc = cb[d];
    const float* up = xz + (size_t)r * 4096 + d;
    if (l >= 3) {
        acc += w[0] * up[-3 * 4096] + w[1] * up[-2 * 4096]
             + w[2] * up[-1 * 4096] + w[3] * up[0];
    } else {
        #pragma unroll
        for (int j = 0; j < 4; ++j) {
            int lj = l - 3 + j;
            if (lj >= 0) acc += w[j] * up[(j - 3) * 4096];
        }
    }
    float sig = 1.f / (1.f + expf(-acc));
    uc[idx] = acc * sig;
}

// ---------------------------------------------------------------------------
// Chunk-parallel selective scan (3 passes).
// ---------------------------------------------------------------------------
__global__ __launch_bounds__(256) void scan_pass1(
    const float* __restrict__ uc,
    const float* __restrict__ dtb,
    const float* __restrict__ xdbl,
    const float* __restrict__ A_log,
    float* __restrict__ Pout,
    float* __restrict__ Hend)
{
    __shared__ __align__(16) float s_u [SCT][16];
    __shared__ __align__(16) float s_dt[SCT][16];
    __shared__ __align__(16) float s_b [SCT][16];

    const int tid  = threadIdx.x;
    const int wave = tid >> 6, lane = tid & 63;
    const int ch   = wave * 4 + (lane >> 4);
    const int n    = lane & 15;
    const int bx   = blockIdx.x;
    const int b    = bx >> 10;
    const int dg   = (bx >> 3) & 127;
    const int chunk = bx & 7;
    const int dbase = dg * 16;
    const int d    = dbase + ch;

    const float A2 = -expf(A_log[d * 16 + n]) * 1.44269504f;

    float h = 0.f, Pp = 1.f;
    const size_t rowbase = (size_t)b * 1024 + chunk * CL;

    for (int w = 0; w < CL; w += SCT) {
        for (int i = tid; i < SCT * 4; i += 256) {
            int tt = i >> 2; int cc = (i & 3) << 2;
            size_t r = rowbase + w + tt;
            *(float4*)&s_u [tt][cc] = *(const float4*)&uc [r * 2048 + dbase + cc];
            *(float4*)&s_dt[tt][cc] = *(const float4*)&dtb[r * 2048 + dbase + cc];
            *(float4*)&s_b [tt][cc] = *(const float4*)&xdbl[r * 96 + 64 + cc];
        }
        __syncthreads();
        #pragma unroll 8
        for (int t = 0; t < SCT; ++t) {
            float dtv = s_dt[t][ch];
            float uv  = s_u[t][ch];
            float dA  = exp2f(dtv * A2);
            h = dA * h + (dtv * uv) * s_b[t][n];
            Pp *= dA;
        }
        __syncthreads();
    }
    size_t idx = (((size_t)(b * CF + chunk) * 2048) + d) * 16 + n;
    Pout[idx] = Pp;
    Hend[idx] = h;
}

__global__ __launch_bounds__(256) void scan_pass2(
    const float* __restrict__ P, const float* __restrict__ Hend,
    float* __restrict__ Hin)
{
    int gid = blockIdx.x * 256 + threadIdx.x;
    int b = gid >> 15;
    int rest = gid & 32767;
    float H = 0.f;
    #pragma unroll
    for (int c = 0; c < CF; ++c) {
        size_t idx = ((size_t)(b * CF + c) << 15) + rest;
        Hin[idx] = H;
        H = P[idx] * H + Hend[idx];
    }
}

__global__ __launch_bounds__(256) void scan_pass3(
    const float* __restrict__ uc,
    const float* __restrict__ dtb,
    const float* __restrict__ xz,
    const float* __restrict__ xdbl,
    const float* __restrict__ A_log,
    const float* __restrict__ Dvec,
    const float* __restrict__ Hin,
    unsigned short* __restrict__ yb)
{
    __shared__ __align__(16) float s_u [SCT][16];
    __shared__ __align__(16) float s_dt[SCT][16];
    __shared__ __align__(16) float s_z [SCT][16];
    __shared__ __align__(16) float s_bc[SCT][32];
    __shared__ __align__(16) float s_y [SCT][16];

    const int tid  = threadIdx.x;
    const int wave = tid >> 6, lane = tid & 63;
    const int ch   = wave * 4 + (lane >> 4);
    const int n    = lane & 15;
    const int bx   = blockIdx.x;
    const int b    = bx >> 10;
    const int dg   = (bx >> 3) & 127;
    const int chunk = bx & 7;
    const int dbase = dg * 16;
    const int d    = dbase + ch;

    const float A2 = -expf(A_log[d * 16 + n]) * 1.44269504f;
    const float Dd = Dvec[d];

    float h = Hin[(((size_t)(b * CF + chunk) * 2048) + d) * 16 + n];
    const size_t rowbase = (size_t)b * 1024 + chunk * CL;

    for (int w = 0; w < CL; w += SCT) {
        for (int i = tid; i < SCT * 4; i += 256) {
            int tt = i >> 2; int cc = (i & 3) << 2;
            size_t r = rowbase + w + tt;
            *(float4*)&s_u [tt][cc] = *(const float4*)&uc [r * 2048 + dbase + cc];
            *(float4*)&s_dt[tt][cc] = *(const float4*)&dtb[r * 2048 + dbase + cc];
            *(float4*)&s_z [tt][cc] = *(const float4*)&xz [r * 4096 + 2048 + dbase + cc];
        }
        for (int i = tid; i < SCT * 8; i += 256) {
            int tt = i >> 3; int cc = (i & 7) << 2;
            size_t r = rowbase + w + tt;
            *(float4*)&s_bc[tt][cc] = *(const float4*)&xdbl[r * 96 + 64 + cc];
        }
        __syncthreads();

        #pragma unroll 4
        for (int t = 0; t < SCT; ++t) {
            float dtv = s_dt[t][ch];
            float uv  = s_u[t][ch];
            float dA  = exp2f(dtv * A2);
            float bn  = s_bc[t][n];
            float cn  = s_bc[t][16 + n];
            h = dA * h + (dtv * uv) * bn;
            float p = h * cn;
            p += __shfl_xor(p, 1);
            p += __shfl_xor(p, 2);
            p += __shfl_xor(p, 4);
            p += __shfl_xor(p, 8);
            if (n == 0) {
                float zv = s_z[t][ch];
                float yv = p + uv * Dd;
                yv *= zv / (1.f + expf(-zv));
                s_y[t][ch] = yv;
            }
        }
        __syncthreads();

        for (int i = tid; i < SCT * 4; i += 256) {
            int tt = i >> 2; int cc = (i & 3) << 2;
            size_t r = rowbase + w + tt;
            float4 v = *(const float4*)&s_y[tt][cc];
            ushort4 o;
            o.x = f2bf(v.x); o.y = f2bf(v.y); o.z = f2bf(v.z); o.w = f2bf(v.w);
            *(ushort4*)&yb[r * 2048 + dbase + cc] = o;
        }
        __syncthreads();
    }
}

extern "C" void kernel_launch(void* const* d_in, const int* in_sizes, int n_in,
                              void* d_out, int out_size, void* d_ws, size_t ws_size,
                              hipStream_t stream)
{
    const float* x      = (const float*)d_in[0];
    const float* W_in   = (const float*)d_in[1];
    const float* conv_w = (const float*)d_in[2];
    const float* conv_b = (const float*)d_in[3];
    const float* W_x    = (const float*)d_in[4];
    const float* W_dt   = (const float*)d_in[5];
    const float* b_dt   = (const float*)d_in[6];
    const float* A_log  = (const float*)d_in[7];
    const float* Dv     = (const float*)d_in[8];
    const float* W_out  = (const float*)d_in[9];
    float* out = (float*)d_out;

    float* ws   = (float*)d_ws;
    float* xz   = ws;                        // [2048][4096] f32
    float* uc   = xz + 8388608;              // [2048][2048] f32
    float* xdbl = uc + 4194304;              // [2048][96]   f32
    float* dtb  = xdbl + 196608;             // [2048][2048] f32
    float* Hend = dtb + 4194304;             // [2][CF][2048][16]
    float* Hin  = Hend + 524288;
    unsigned short* bfbase = (unsigned short*)(Hin + 524288);
    unsigned short* xb   = bfbase;           // [2048][1024] bf16
    unsigned short* wbT  = xb + 2097152;     // [4096][1024] bf16 (W_in^T)
    unsigned short* wobT = wbT + 4194304;    // [1024][2048] bf16 (W_out^T)
    unsigned short* yb   = wbT;              // aliases wbT (dead after GEMM1)
    float* Pbuf = (float*)xb;                // aliases xb (dead after GEMM1)

    dim3 blk(256);

    // prep
    transpose_cast<<<dim3(128, 32), blk, 0, stream>>>(W_in, wbT, 1024, 4096);
    transpose_cast<<<dim3(32, 64), blk, 0, stream>>>(W_out, wobT, 2048, 1024);
    cast_bf16<<<2048, blk, 0, stream>>>(x, xb);

    // 1. xz = x @ W_in          (bf16 MFMA, 512 blocks)
    gemm_bf16<128><<<dim3(32, 16), blk, 0, stream>>>(xb, wbT, xz, 1024, 1024, 1024, 4096);

    // 2. u_c = silu(conv(u) + cb)
    conv_silu_kernel<<<(2048 * 2048) / 256, blk, 0, stream>>>(xz, conv_w, conv_b, uc);

    // 3. x_dbl = u_c @ W_x      (fp32 split-K, 512 blocks + atomics)
    zero_f32<<<192, blk, 0, stream>>>(xdbl);
    gemm_f32_splitk<<<512, blk, 0, stream>>>(uc, W_x, xdbl);

    // 4. dt = softplus(x_dbl[:, :64] @ W_dt + b_dt)   (fp32, 1024 blocks)
    gemm_f32<<<dim3(32, 32), blk, 0, stream>>>(
        xdbl, W_dt, dtb, 2048, 2048, 64, 96, 2048, 2048, 1, b_dt);

    // 5. chunk-parallel scan
    scan_pass1<<<2048, blk, 0, stream>>>(uc, dtb, xdbl, A_log, Pbuf, Hend);
    scan_pass2<<<256, blk, 0, stream>>>(Pbuf, Hend, Hin);
    scan_pass3<<<2048, blk, 0, stream>>>(uc, dtb, xz, xdbl, A_log, Dv, Hin, yb);

    // 6. out = y @ W_out        (bf16 MFMA, 256 blocks)
    gemm_bf16<64><<<dim3(8, 32), blk, 0, stream>>>(yb, wobT, out, 2048, 2048, 2048, 1024);
}

// Round 6
// 365.195 us; speedup vs baseline: 3.2609x; 1.0996x over previous
//
#include <hip/hip_runtime.h>
#include <hip/hip_bf16.h>

// ---------------------------------------------------------------------------
// Mamba block forward. Round 6: register-state chunk scan (thread per
// (b,d,chunk), h[16] in VGPRs, no shuffles), scalar decay-sum trick,
// GEMM1 split epilogue (u fp32 / z bf16), dtb aliases u_pre.
// B=2 L=1024 DM=1024 DI=2048 DS=16 DTR=64
// ---------------------------------------------------------------------------

typedef __attribute__((ext_vector_type(8))) short bfrag;
typedef __attribute__((ext_vector_type(4))) float f32x4;

#define CF   32   // scan time-chunks
#define CLEN 32   // steps per chunk (CF*CLEN = 1024)

__device__ __forceinline__ unsigned short f2bf(float f) {
    unsigned int u = __float_as_uint(f);
    u += 0x7FFF + ((u >> 16) & 1);          // round-to-nearest-even
    return (unsigned short)(u >> 16);
}
__device__ __forceinline__ float bf2f(unsigned short s) {
    return __uint_as_float((unsigned int)s << 16);
}

// ---------------- bf16 MFMA GEMM: C[M][N] = A[M][K] * BT[N][K]^T ------------
// split>0: col<split -> fp32 C (ld=split); col>=split -> bf16 C1 (ld=split)
template<int MT>
__global__ __launch_bounds__(256) void gemm_bf16(
    const unsigned short* __restrict__ A,   // [M][K] bf16
    const unsigned short* __restrict__ BT,  // [N][K] bf16
    float* __restrict__ C,
    unsigned short* __restrict__ C1,
    int K, int lda, int ldb, int ldc, int split)
{
    constexpr int FJ = (MT == 128) ? 4 : 2;
    __shared__ unsigned short sA[MT][40];
    __shared__ unsigned short sB[128][40];

    const int tid  = threadIdx.x;
    const int wave = tid >> 6, lane = tid & 63;
    const int lm   = lane & 15;
    const int quad = lane >> 4;
    const int kb   = quad << 3;
    const int wrow = (MT == 128) ? ((wave >> 1) << 6) : 0;
    const int wcol = (MT == 128) ? ((wave & 1) << 6) : (wave << 5);
    const int bm = blockIdx.y * MT, bn = blockIdx.x * 128;

    const int srow = tid >> 2;
    const int scol = (tid & 3) << 3;

    f32x4 acc[4][FJ];
    #pragma unroll
    for (int i = 0; i < 4; ++i)
        #pragma unroll
        for (int j = 0; j < FJ; ++j) {
            acc[i][j][0] = 0.f; acc[i][j][1] = 0.f;
            acc[i][j][2] = 0.f; acc[i][j][3] = 0.f;
        }

    for (int k0 = 0; k0 < K; k0 += 32) {
        *(float4*)&sA[srow][scol] = *(const float4*)&A[(size_t)(bm + srow) * lda + k0 + scol];
        if (MT == 128)
            *(float4*)&sA[srow + 64][scol] = *(const float4*)&A[(size_t)(bm + srow + 64) * lda + k0 + scol];
        *(float4*)&sB[srow][scol]      = *(const float4*)&BT[(size_t)(bn + srow)      * ldb + k0 + scol];
        *(float4*)&sB[srow + 64][scol] = *(const float4*)&BT[(size_t)(bn + srow + 64) * ldb + k0 + scol];
        __syncthreads();

        bfrag af[4], bf[FJ];
        #pragma unroll
        for (int i = 0; i < 4; ++i) af[i] = *(const bfrag*)&sA[wrow + i * 16 + lm][kb];
        #pragma unroll
        for (int j = 0; j < FJ; ++j) bf[j] = *(const bfrag*)&sB[wcol + j * 16 + lm][kb];

        #pragma unroll
        for (int i = 0; i < 4; ++i)
            #pragma unroll
            for (int j = 0; j < FJ; ++j)
                acc[i][j] = __builtin_amdgcn_mfma_f32_16x16x32_bf16(
                    af[i], bf[j], acc[i][j], 0, 0, 0);
        __syncthreads();
    }

    // C/D layout: col = lane&15, row = quad*4 + reg
    #pragma unroll
    for (int i = 0; i < 4; ++i)
        #pragma unroll
        for (int j = 0; j < FJ; ++j) {
            const int col = bn + wcol + j * 16 + lm;
            #pragma unroll
            for (int r = 0; r < 4; ++r) {
                const int row = bm + wrow + i * 16 + quad * 4 + r;
                float v = acc[i][j][r];
                if (split > 0) {
                    if (col < split) C [(size_t)row * split + col] = v;
                    else             C1[(size_t)row * split + (col - split)] = f2bf(v);
                } else {
                    C[(size_t)row * ldc + col] = v;
                }
            }
        }
}

// ---------------- transpose + cast ------------------------------------------
__global__ __launch_bounds__(256) void transpose_cast(
    const float* __restrict__ in, unsigned short* __restrict__ out,
    int rows, int cols)
{
    __shared__ float tile[32][33];
    const int j0 = blockIdx.x * 32, i0 = blockIdx.y * 32;
    const int tx = threadIdx.x & 31, ty = threadIdx.x >> 5;
    #pragma unroll
    for (int k = 0; k < 4; ++k)
        tile[ty + 8 * k][tx] = in[(size_t)(i0 + ty + 8 * k) * cols + j0 + tx];
    __syncthreads();
    #pragma unroll
    for (int k = 0; k < 4; ++k)
        out[(size_t)(j0 + ty + 8 * k) * rows + i0 + tx] = f2bf(tile[tx][ty + 8 * k]);
}

__global__ __launch_bounds__(256) void cast_bf16(
    const float* __restrict__ in, unsigned short* __restrict__ out)
{
    int i = (blockIdx.x * 256 + threadIdx.x) * 4;
    float4 v = *(const float4*)&in[i];
    ushort4 o;
    o.x = f2bf(v.x); o.y = f2bf(v.y); o.z = f2bf(v.z); o.w = f2bf(v.w);
    *(ushort4*)&out[i] = o;
}

__global__ __launch_bounds__(256) void zero_f32(float* __restrict__ p)
{
    int i = (blockIdx.x * 256 + threadIdx.x) * 4;
    *(float4*)&p[i] = float4{0.f, 0.f, 0.f, 0.f};
}

// ---------------- split-K fp32 GEMM: x_dbl = u_c @ W_x ----------------------
#define SK_KS 128
__global__ __launch_bounds__(256) void gemm_f32_splitk(
    const float* __restrict__ A, const float* __restrict__ B,
    float* __restrict__ C)
{
    __shared__ __align__(16) float As[16][64];
    __shared__ __align__(16) float Bs[16][96];

    const int tid = threadIdx.x;
    const int mtile = blockIdx.x >> 4;
    const int kslice = blockIdx.x & 15;
    const int bm = mtile * 64;
    const int kbase = kslice * SK_KS;

    const int am = tid >> 2;
    const int ak = (tid & 3) << 2;

    const int ty = tid >> 4, tx = tid & 15;
    const int rm = ty << 2;
    const int rn = tx * 6;

    float acc[4][6] = {};

    for (int k0 = 0; k0 < SK_KS; k0 += 16) {
        float4 av = *(const float4*)&A[(size_t)(bm + am) * 2048 + kbase + k0 + ak];
        As[ak + 0][am] = av.x;
        As[ak + 1][am] = av.y;
        As[ak + 2][am] = av.z;
        As[ak + 3][am] = av.w;
        for (int i = tid; i < 384; i += 256) {
            int br = i / 24, bc = (i % 24) << 2;
            *(float4*)&Bs[br][bc] = *(const float4*)&B[(size_t)(kbase + k0 + br) * 96 + bc];
        }
        __syncthreads();

        #pragma unroll
        for (int k = 0; k < 16; ++k) {
            float4 a = *(const float4*)&As[k][rm];
            float b[6];
            #pragma unroll
            for (int j = 0; j < 6; ++j) b[j] = Bs[k][rn + j];
            #pragma unroll
            for (int j = 0; j < 6; ++j) {
                acc[0][j] += a.x * b[j];
                acc[1][j] += a.y * b[j];
                acc[2][j] += a.z * b[j];
                acc[3][j] += a.w * b[j];
            }
        }
        __syncthreads();
    }

    #pragma unroll
    for (int i = 0; i < 4; ++i) {
        float* crow = C + (size_t)(bm + rm + i) * 96 + rn;
        #pragma unroll
        for (int j = 0; j < 6; ++j)
            atomicAdd(&crow[j], acc[i][j]);
    }
}

// ---------------- fp32 tiled GEMM (dt GEMM) ---------------------------------
#define BM 64
#define BN 64
#define BK 16
__global__ __launch_bounds__(256) void gemm_f32(
    const float* __restrict__ A, const float* __restrict__ B,
    float* __restrict__ C, int M, int N, int K,
    int lda, int ldb, int ldc, int mode, const float* __restrict__ bias)
{
    __shared__ __align__(16) float As[BK][BM];
    __shared__ __align__(16) float Bs[BK][BN];

    const int tid = threadIdx.x;
    const int bm = blockIdx.y * BM;
    const int bn = blockIdx.x * BN;

    const int am = tid >> 2;
    const int ak = (tid & 3) << 2;
    const int bk = tid >> 4;
    const int bnn = (tid & 15) << 2;

    const int tx = tid & 15, ty = tid >> 4;
    const int rm = ty << 2;
    const int rn = tx << 2;
    const int cm = bm + rm, cn = bn + rn;

    float acc[4][4] = {};

    for (int k0 = 0; k0 < K; k0 += BK) {
        const float* ap = A + (size_t)(bm + am) * lda + (k0 + ak);
        float4 av = *(const float4*)ap;
        As[ak + 0][am] = av.x;
        As[ak + 1][am] = av.y;
        As[ak + 2][am] = av.z;
        As[ak + 3][am] = av.w;
        {
            const int ncol = bn + bnn;
            const float* bp = B + (size_t)(k0 + bk) * ldb + ncol;
            float4 bv;
            if (ncol + 3 < N) {
                bv = *(const float4*)bp;
            } else {
                bv.x = (ncol + 0 < N) ? bp[0] : 0.f;
                bv.y = (ncol + 1 < N) ? bp[1] : 0.f;
                bv.z = (ncol + 2 < N) ? bp[2] : 0.f;
                bv.w = (ncol + 3 < N) ? bp[3] : 0.f;
            }
            *(float4*)&Bs[bk][bnn] = bv;
        }
        __syncthreads();

        #pragma unroll
        for (int k = 0; k < BK; ++k) {
            float4 a = *(const float4*)&As[k][rm];
            float4 b = *(const float4*)&Bs[k][rn];
            acc[0][0] += a.x * b.x; acc[0][1] += a.x * b.y;
            acc[0][2] += a.x * b.z; acc[0][3] += a.x * b.w;
            acc[1][0] += a.y * b.x; acc[1][1] += a.y * b.y;
            acc[1][2] += a.y * b.z; acc[1][3] += a.y * b.w;
            acc[2][0] += a.z * b.x; acc[2][1] += a.z * b.y;
            acc[2][2] += a.z * b.z; acc[2][3] += a.z * b.w;
            acc[3][0] += a.w * b.x; acc[3][1] += a.w * b.y;
            acc[3][2] += a.w * b.z; acc[3][3] += a.w * b.w;
        }
        __syncthreads();
    }

    #pragma unroll
    for (int i = 0; i < 4; ++i) {
        float* crow = C + (size_t)(cm + i) * ldc;
        #pragma unroll
        for (int j = 0; j < 4; ++j) {
            int col = cn + j;
            if (col < N) {
                float v = acc[i][j];
                if (mode == 1) {
                    v += bias[col];
                    v = (v > 20.f) ? v : logf(1.f + expf(v));  // softplus
                }
                crow[col] = v;
            }
        }
    }
}

// ---------------- depthwise causal conv(4) + bias + SiLU --------------------
// reads contiguous u_pre [2048][2048] fp32, writes uc [2048][2048] fp32
__global__ __launch_bounds__(256) void conv_silu_kernel(
    const float* __restrict__ upre, const float* __restrict__ cw,
    const float* __restrict__ cb, float* __restrict__ uc)
{
    int idx = blockIdx.x * 256 + threadIdx.x;
    int d = idx & 2047;
    int r = idx >> 11;
    int l = r & 1023;

    float4 w4 = *(const float4*)(cw + 4 * d);
    float w[4] = { w4.x, w4.y, w4.z, w4.w };
    float acc = cb[d];
    const float* up = upre + (size_t)r * 2048 + d;
    if (l >= 3) {
        acc += w[0] * up[-3 * 2048] + w[1] * up[-2 * 2048]
             + w[2] * up[-1 * 2048] + w[3] * up[0];
    } else {
        #pragma unroll
        for (int j = 0; j < 4; ++j) {
            int lj = l - 3 + j;
            if (lj >= 0) acc += w[j] * up[(j - 3) * 2048];
        }
    }
    float sig = 1.f / (1.f + expf(-acc));
    uc[idx] = acc * sig;
}

// ---------------------------------------------------------------------------
// Register-state chunk-parallel scan.
// Thread = one (batch, channel, chunk); h[16] in VGPRs. Block = 256 channels.
// Grid = 2 batches x 8 ch-groups x CF chunks = 512 blocks.
// blockIdx.x = b*256 + g*CF + c  (bits: c=0..4, g=5..7, b=8)
// ---------------------------------------------------------------------------

// Pass 1: local scan from h=0 -> Hend; decay summarized by sdt = sum(dt).
__global__ __launch_bounds__(256) void scan_pass1(
    const float* __restrict__ uc,     // [2048][2048]
    const float* __restrict__ dtb,    // [2048][2048]
    const float* __restrict__ xdbl,   // [2048][96], B@64
    const float* __restrict__ A_log,  // [2048][16]
    float* __restrict__ Hend,         // [2][CF][2048][16]
    float* __restrict__ Sdt)          // [2][CF][2048]
{
    __shared__ float sB[CLEN][16];
    const int tid = threadIdx.x;
    const int bx  = blockIdx.x;
    const int c   = bx & (CF - 1);
    const int g   = (bx >> 5) & 7;
    const int b   = bx >> 8;
    const int d   = g * 256 + tid;
    const size_t rowbase = (size_t)b * 1024 + c * CLEN;

    for (int i = tid; i < CLEN * 16; i += 256) {
        int tt = i >> 4, nn = i & 15;
        sB[tt][nn] = xdbl[(rowbase + tt) * 96 + 64 + nn];
    }

    float A2[16];
    {
        float al[16];
        #pragma unroll
        for (int q = 0; q < 4; ++q)
            *(float4*)&al[4 * q] = *(const float4*)&A_log[(size_t)d * 16 + 4 * q];
        #pragma unroll
        for (int n = 0; n < 16; ++n) A2[n] = -expf(al[n]) * 1.44269504f;
    }
    __syncthreads();

    float h[16];
    #pragma unroll
    for (int n = 0; n < 16; ++n) h[n] = 0.f;
    float sdt = 0.f;

    #pragma unroll 4
    for (int t = 0; t < CLEN; ++t) {
        size_t r = rowbase + t;
        float dtv = dtb[r * 2048 + d];
        float uv  = uc [r * 2048 + d];
        sdt += dtv;
        float dtu = dtv * uv;
        float bl[16];
        #pragma unroll
        for (int q = 0; q < 4; ++q)
            *(float4*)&bl[4 * q] = *(const float4*)&sB[t][4 * q];
        #pragma unroll
        for (int n = 0; n < 16; ++n)
            h[n] = exp2f(dtv * A2[n]) * h[n] + dtu * bl[n];
    }

    size_t base = ((size_t)(b * CF + c) * 2048 + d) * 16;
    #pragma unroll
    for (int q = 0; q < 4; ++q)
        *(float4*)&Hend[base + 4 * q] = *(float4*)&h[4 * q];
    Sdt[(size_t)(b * CF + c) * 2048 + d] = sdt;
}

// Pass 2: serial combine over CF chunks; P[n] = exp2(A2[n]*Sdt).
__global__ __launch_bounds__(256) void scan_pass2(
    const float* __restrict__ Hend, const float* __restrict__ Sdt,
    const float* __restrict__ A_log, float* __restrict__ Hin)
{
    int gid = blockIdx.x * 256 + threadIdx.x;   // 0..65535
    int b = gid >> 15;
    int rest = gid & 32767;                     // d*16+n
    int d = rest >> 4;
    float A2 = -expf(A_log[rest]) * 1.44269504f;
    float H = 0.f;
    #pragma unroll
    for (int c = 0; c < CF; ++c) {
        size_t sidx = (size_t)(b * CF + c) * 2048 + d;
        size_t idx  = ((size_t)(b * CF + c) << 15) + rest;
        Hin[idx] = H;
        H = exp2f(A2 * Sdt[sidx]) * H + Hend[idx];
    }
}

// Pass 3: replay from Hin; fused epilogue y=(scan+u*D)*silu(z) -> bf16.
__global__ __launch_bounds__(256) void scan_pass3(
    const float* __restrict__ uc,
    const float* __restrict__ dtb,
    const unsigned short* __restrict__ zb,  // [2048][2048] bf16
    const float* __restrict__ xdbl,         // B@64, C@80
    const float* __restrict__ A_log,
    const float* __restrict__ Dvec,
    const float* __restrict__ Hin,
    unsigned short* __restrict__ yb)        // [2048][2048] bf16
{
    __shared__ float sBC[CLEN][32];
    const int tid = threadIdx.x;
    const int bx  = blockIdx.x;
    const int c   = bx & (CF - 1);
    const int g   = (bx >> 5) & 7;
    const int b   = bx >> 8;
    const int d   = g * 256 + tid;
    const size_t rowbase = (size_t)b * 1024 + c * CLEN;

    for (int i = tid; i < CLEN * 32; i += 256) {
        int tt = i >> 5, j = i & 31;
        sBC[tt][j] = xdbl[(rowbase + tt) * 96 + 64 + j];
    }

    float A2[16];
    {
        float al[16];
        #pragma unroll
        for (int q = 0; q < 4; ++q)
            *(float4*)&al[4 * q] = *(const float4*)&A_log[(size_t)d * 16 + 4 * q];
        #pragma unroll
        for (int n = 0; n < 16; ++n) A2[n] = -expf(al[n]) * 1.44269504f;
    }
    const float Dd = Dvec[d];

    float h[16];
    {
        size_t base = ((size_t)(b * CF + c) * 2048 + d) * 16;
        #pragma unroll
        for (int q = 0; q < 4; ++q)
            *(float4*)&h[4 * q] = *(const float4*)&Hin[base + 4 * q];
    }
    __syncthreads();

    #pragma unroll 2
    for (int t = 0; t < CLEN; ++t) {
        size_t r = rowbase + t;
        float dtv = dtb[r * 2048 + d];
        float uv  = uc [r * 2048 + d];
        float zv  = bf2f(zb[r * 2048 + d]);
        float dtu = dtv * uv;
        float bl[16], cl[16];
        #pragma unroll
        for (int q = 0; q < 4; ++q) {
            *(float4*)&bl[4 * q] = *(const float4*)&sBC[t][4 * q];
            *(float4*)&cl[4 * q] = *(const float4*)&sBC[t][16 + 4 * q];
        }
        float acc = uv * Dd;
        #pragma unroll
        for (int n = 0; n < 16; ++n) {
            h[n] = exp2f(dtv * A2[n]) * h[n] + dtu * bl[n];
            acc += h[n] * cl[n];
        }
        float yv = acc * zv / (1.f + expf(-zv));
        yb[r * 2048 + d] = f2bf(yv);
    }
}

extern "C" void kernel_launch(void* const* d_in, const int* in_sizes, int n_in,
                              void* d_out, int out_size, void* d_ws, size_t ws_size,
                              hipStream_t stream)
{
    const float* x      = (const float*)d_in[0];
    const float* W_in   = (const float*)d_in[1];
    const float* conv_w = (const float*)d_in[2];
    const float* conv_b = (const float*)d_in[3];
    const float* W_x    = (const float*)d_in[4];
    const float* W_dt   = (const float*)d_in[5];
    const float* b_dt   = (const float*)d_in[6];
    const float* A_log  = (const float*)d_in[7];
    const float* Dv     = (const float*)d_in[8];
    const float* W_out  = (const float*)d_in[9];
    float* out = (float*)d_out;

    float* ws    = (float*)d_ws;
    float* upre  = ws;                       // [2048][2048] f32 (GEMM1 u half)
    float* dtb   = upre;                     // ALIAS: dt overwrites u_pre
                                             //   (u_pre dead after conv)
    float* uc    = ws + 4194304;             // [2048][2048] f32
    float* xdbl  = uc + 4194304;             // [2048][96]   f32
    float* Hend  = xdbl + 196608;            // [2][CF][2048][16] = 2097152
    float* Hin   = Hend + 2097152;           // 2097152
    float* Sdt   = Hin + 2097152;            // [2][CF][2048] = 131072
    unsigned short* zb   = (unsigned short*)(Sdt + 131072);  // [2048][2048] bf16
    unsigned short* xb   = zb + 4194304;     // [2048][1024] bf16
    unsigned short* wbT  = xb + 2097152;     // [4096][1024] bf16 (W_in^T)
    unsigned short* wobT = wbT + 4194304;    // [1024][2048] bf16 (W_out^T)
    unsigned short* yb   = wbT;              // aliases wbT (dead after GEMM1)

    dim3 blk(256);

    // prep
    transpose_cast<<<dim3(128, 32), blk, 0, stream>>>(W_in, wbT, 1024, 4096);
    transpose_cast<<<dim3(32, 64), blk, 0, stream>>>(W_out, wobT, 2048, 1024);
    cast_bf16<<<2048, blk, 0, stream>>>(x, xb);

    // 1. xz = x @ W_in   (bf16 MFMA; split epilogue: u fp32, z bf16)
    gemm_bf16<128><<<dim3(32, 16), blk, 0, stream>>>(
        xb, wbT, upre, zb, 1024, 1024, 1024, 0, 2048);

    // 2. u_c = silu(conv(u) + cb)
    conv_silu_kernel<<<(2048 * 2048) / 256, blk, 0, stream>>>(upre, conv_w, conv_b, uc);

    // 3. x_dbl = u_c @ W_x   (fp32 split-K + atomics)
    zero_f32<<<192, blk, 0, stream>>>(xdbl);
    gemm_f32_splitk<<<512, blk, 0, stream>>>(uc, W_x, xdbl);

    // 4. dt = softplus(x_dbl[:, :64] @ W_dt + b_dt)  (fp32; dtb aliases upre)
    gemm_f32<<<dim3(32, 32), blk, 0, stream>>>(
        xdbl, W_dt, dtb, 2048, 2048, 64, 96, 2048, 2048, 1, b_dt);

    // 5. register-state chunk scan
    scan_pass1<<<512, blk, 0, stream>>>(uc, dtb, xdbl, A_log, Hend, Sdt);
    scan_pass2<<<256, blk, 0, stream>>>(Hend, Sdt, A_log, Hin);
    scan_pass3<<<512, blk, 0, stream>>>(uc, dtb, zb, xdbl, A_log, Dv, Hin, yb);

    // 6. out = y @ W_out   (bf16 MFMA)
    gemm_bf16<64><<<dim3(8, 32), blk, 0, stream>>>(
        yb, wobT, out, nullptr, 2048, 2048, 2048, 1024, 0);
}

// Round 7
// 296.143 us; speedup vs baseline: 4.0212x; 1.2332x over previous
//
#include <hip/hip_runtime.h>
#include <hip/hip_bf16.h>

// ---------------------------------------------------------------------------
// Mamba block forward. Round 7: split-K GEMM3 with partial buffers + reduce
// (atomicAdd epilogue was 73.7 MB of HBM-side RMW -> 93 us).
// B=2 L=1024 DM=1024 DI=2048 DS=16 DTR=64
// ---------------------------------------------------------------------------

typedef __attribute__((ext_vector_type(8))) short bfrag;
typedef __attribute__((ext_vector_type(4))) float f32x4;

#define CF   32   // scan time-chunks
#define CLEN 32   // steps per chunk (CF*CLEN = 1024)

__device__ __forceinline__ unsigned short f2bf(float f) {
    unsigned int u = __float_as_uint(f);
    u += 0x7FFF + ((u >> 16) & 1);          // round-to-nearest-even
    return (unsigned short)(u >> 16);
}
__device__ __forceinline__ float bf2f(unsigned short s) {
    return __uint_as_float((unsigned int)s << 16);
}

// ---------------- bf16 MFMA GEMM: C[M][N] = A[M][K] * BT[N][K]^T ------------
// split>0: col<split -> fp32 C (ld=split); col>=split -> bf16 C1 (ld=split)
template<int MT>
__global__ __launch_bounds__(256) void gemm_bf16(
    const unsigned short* __restrict__ A,   // [M][K] bf16
    const unsigned short* __restrict__ BT,  // [N][K] bf16
    float* __restrict__ C,
    unsigned short* __restrict__ C1,
    int K, int lda, int ldb, int ldc, int split)
{
    constexpr int FJ = (MT == 128) ? 4 : 2;
    __shared__ unsigned short sA[MT][40];
    __shared__ unsigned short sB[128][40];

    const int tid  = threadIdx.x;
    const int wave = tid >> 6, lane = tid & 63;
    const int lm   = lane & 15;
    const int quad = lane >> 4;
    const int kb   = quad << 3;
    const int wrow = (MT == 128) ? ((wave >> 1) << 6) : 0;
    const int wcol = (MT == 128) ? ((wave & 1) << 6) : (wave << 5);
    const int bm = blockIdx.y * MT, bn = blockIdx.x * 128;

    const int srow = tid >> 2;
    const int scol = (tid & 3) << 3;

    f32x4 acc[4][FJ];
    #pragma unroll
    for (int i = 0; i < 4; ++i)
        #pragma unroll
        for (int j = 0; j < FJ; ++j) {
            acc[i][j][0] = 0.f; acc[i][j][1] = 0.f;
            acc[i][j][2] = 0.f; acc[i][j][3] = 0.f;
        }

    for (int k0 = 0; k0 < K; k0 += 32) {
        *(float4*)&sA[srow][scol] = *(const float4*)&A[(size_t)(bm + srow) * lda + k0 + scol];
        if (MT == 128)
            *(float4*)&sA[srow + 64][scol] = *(const float4*)&A[(size_t)(bm + srow + 64) * lda + k0 + scol];
        *(float4*)&sB[srow][scol]      = *(const float4*)&BT[(size_t)(bn + srow)      * ldb + k0 + scol];
        *(float4*)&sB[srow + 64][scol] = *(const float4*)&BT[(size_t)(bn + srow + 64) * ldb + k0 + scol];
        __syncthreads();

        bfrag af[4], bf[FJ];
        #pragma unroll
        for (int i = 0; i < 4; ++i) af[i] = *(const bfrag*)&sA[wrow + i * 16 + lm][kb];
        #pragma unroll
        for (int j = 0; j < FJ; ++j) bf[j] = *(const bfrag*)&sB[wcol + j * 16 + lm][kb];

        #pragma unroll
        for (int i = 0; i < 4; ++i)
            #pragma unroll
            for (int j = 0; j < FJ; ++j)
                acc[i][j] = __builtin_amdgcn_mfma_f32_16x16x32_bf16(
                    af[i], bf[j], acc[i][j], 0, 0, 0);
        __syncthreads();
    }

    // C/D layout: col = lane&15, row = quad*4 + reg
    #pragma unroll
    for (int i = 0; i < 4; ++i)
        #pragma unroll
        for (int j = 0; j < FJ; ++j) {
            const int col = bn + wcol + j * 16 + lm;
            #pragma unroll
            for (int r = 0; r < 4; ++r) {
                const int row = bm + wrow + i * 16 + quad * 4 + r;
                float v = acc[i][j][r];
                if (split > 0) {
                    if (col < split) C [(size_t)row * split + col] = v;
                    else             C1[(size_t)row * split + (col - split)] = f2bf(v);
                } else {
                    C[(size_t)row * ldc + col] = v;
                }
            }
        }
}

// ---------------- transpose + cast ------------------------------------------
__global__ __launch_bounds__(256) void transpose_cast(
    const float* __restrict__ in, unsigned short* __restrict__ out,
    int rows, int cols)
{
    __shared__ float tile[32][33];
    const int j0 = blockIdx.x * 32, i0 = blockIdx.y * 32;
    const int tx = threadIdx.x & 31, ty = threadIdx.x >> 5;
    #pragma unroll
    for (int k = 0; k < 4; ++k)
        tile[ty + 8 * k][tx] = in[(size_t)(i0 + ty + 8 * k) * cols + j0 + tx];
    __syncthreads();
    #pragma unroll
    for (int k = 0; k < 4; ++k)
        out[(size_t)(j0 + ty + 8 * k) * rows + i0 + tx] = f2bf(tile[tx][ty + 8 * k]);
}

__global__ __launch_bounds__(256) void cast_bf16(
    const float* __restrict__ in, unsigned short* __restrict__ out)
{
    int i = (blockIdx.x * 256 + threadIdx.x) * 4;
    float4 v = *(const float4*)&in[i];
    ushort4 o;
    o.x = f2bf(v.x); o.y = f2bf(v.y); o.z = f2bf(v.z); o.w = f2bf(v.w);
    *(ushort4*)&out[i] = o;
}

// ---------------- split-K fp32 GEMM: part[ks] = u_c @ W_x (K-slice) ---------
#define SK_KS 128
__global__ __launch_bounds__(256) void gemm_f32_splitk(
    const float* __restrict__ A, const float* __restrict__ B,
    float* __restrict__ part)                // [16][2048][96]
{
    __shared__ __align__(16) float As[16][64];
    __shared__ __align__(16) float Bs[16][96];

    const int tid = threadIdx.x;
    const int mtile = blockIdx.x >> 4;
    const int kslice = blockIdx.x & 15;
    const int bm = mtile * 64;
    const int kbase = kslice * SK_KS;

    const int am = tid >> 2;
    const int ak = (tid & 3) << 2;

    const int ty = tid >> 4, tx = tid & 15;
    const int rm = ty << 2;
    const int rn = tx * 6;

    float acc[4][6] = {};

    for (int k0 = 0; k0 < SK_KS; k0 += 16) {
        float4 av = *(const float4*)&A[(size_t)(bm + am) * 2048 + kbase + k0 + ak];
        As[ak + 0][am] = av.x;
        As[ak + 1][am] = av.y;
        As[ak + 2][am] = av.z;
        As[ak + 3][am] = av.w;
        for (int i = tid; i < 384; i += 256) {
            int br = i / 24, bc = (i % 24) << 2;
            *(float4*)&Bs[br][bc] = *(const float4*)&B[(size_t)(kbase + k0 + br) * 96 + bc];
        }
        __syncthreads();

        #pragma unroll
        for (int k = 0; k < 16; ++k) {
            float4 a = *(const float4*)&As[k][rm];
            float b[6];
            #pragma unroll
            for (int j = 0; j < 6; ++j) b[j] = Bs[k][rn + j];
            #pragma unroll
            for (int j = 0; j < 6; ++j) {
                acc[0][j] += a.x * b[j];
                acc[1][j] += a.y * b[j];
                acc[2][j] += a.z * b[j];
                acc[3][j] += a.w * b[j];
            }
        }
        __syncthreads();
    }

    float* pout = part + (size_t)kslice * 196608;
    #pragma unroll
    for (int i = 0; i < 4; ++i) {
        float* crow = pout + (size_t)(bm + rm + i) * 96 + rn;
        #pragma unroll
        for (int j = 0; j < 6; ++j)
            crow[j] = acc[i][j];
    }
}

// ---------------- reduce 16 split-K partials -> xdbl ------------------------
__global__ __launch_bounds__(256) void reduce_splitk(
    const float* __restrict__ part, float* __restrict__ xdbl)
{
    int i = (blockIdx.x * 256 + threadIdx.x) * 4;   // < 196608
    float4 acc = {0.f, 0.f, 0.f, 0.f};
    #pragma unroll
    for (int s = 0; s < 16; ++s) {
        float4 v = *(const float4*)&part[(size_t)s * 196608 + i];
        acc.x += v.x; acc.y += v.y; acc.z += v.z; acc.w += v.w;
    }
    *(float4*)&xdbl[i] = acc;
}

// ---------------- fp32 tiled GEMM (dt GEMM) ---------------------------------
#define BM 64
#define BN 64
#define BK 16
__global__ __launch_bounds__(256) void gemm_f32(
    const float* __restrict__ A, const float* __restrict__ B,
    float* __restrict__ C, int M, int N, int K,
    int lda, int ldb, int ldc, int mode, const float* __restrict__ bias)
{
    __shared__ __align__(16) float As[BK][BM];
    __shared__ __align__(16) float Bs[BK][BN];

    const int tid = threadIdx.x;
    const int bm = blockIdx.y * BM;
    const int bn = blockIdx.x * BN;

    const int am = tid >> 2;
    const int ak = (tid & 3) << 2;
    const int bk = tid >> 4;
    const int bnn = (tid & 15) << 2;

    const int tx = tid & 15, ty = tid >> 4;
    const int rm = ty << 2;
    const int rn = tx << 2;
    const int cm = bm + rm, cn = bn + rn;

    float acc[4][4] = {};

    for (int k0 = 0; k0 < K; k0 += BK) {
        const float* ap = A + (size_t)(bm + am) * lda + (k0 + ak);
        float4 av = *(const float4*)ap;
        As[ak + 0][am] = av.x;
        As[ak + 1][am] = av.y;
        As[ak + 2][am] = av.z;
        As[ak + 3][am] = av.w;
        {
            const int ncol = bn + bnn;
            const float* bp = B + (size_t)(k0 + bk) * ldb + ncol;
            float4 bv;
            if (ncol + 3 < N) {
                bv = *(const float4*)bp;
            } else {
                bv.x = (ncol + 0 < N) ? bp[0] : 0.f;
                bv.y = (ncol + 1 < N) ? bp[1] : 0.f;
                bv.z = (ncol + 2 < N) ? bp[2] : 0.f;
                bv.w = (ncol + 3 < N) ? bp[3] : 0.f;
            }
            *(float4*)&Bs[bk][bnn] = bv;
        }
        __syncthreads();

        #pragma unroll
        for (int k = 0; k < BK; ++k) {
            float4 a = *(const float4*)&As[k][rm];
            float4 b = *(const float4*)&Bs[k][rn];
            acc[0][0] += a.x * b.x; acc[0][1] += a.x * b.y;
            acc[0][2] += a.x * b.z; acc[0][3] += a.x * b.w;
            acc[1][0] += a.y * b.x; acc[1][1] += a.y * b.y;
            acc[1][2] += a.y * b.z; acc[1][3] += a.y * b.w;
            acc[2][0] += a.z * b.x; acc[2][1] += a.z * b.y;
            acc[2][2] += a.z * b.z; acc[2][3] += a.z * b.w;
            acc[3][0] += a.w * b.x; acc[3][1] += a.w * b.y;
            acc[3][2] += a.w * b.z; acc[3][3] += a.w * b.w;
        }
        __syncthreads();
    }

    #pragma unroll
    for (int i = 0; i < 4; ++i) {
        float* crow = C + (size_t)(cm + i) * ldc;
        #pragma unroll
        for (int j = 0; j < 4; ++j) {
            int col = cn + j;
            if (col < N) {
                float v = acc[i][j];
                if (mode == 1) {
                    v += bias[col];
                    v = (v > 20.f) ? v : logf(1.f + expf(v));  // softplus
                }
                crow[col] = v;
            }
        }
    }
}

// ---------------- depthwise causal conv(4) + bias + SiLU --------------------
__global__ __launch_bounds__(256) void conv_silu_kernel(
    const float* __restrict__ upre, const float* __restrict__ cw,
    const float* __restrict__ cb, float* __restrict__ uc)
{
    int idx = blockIdx.x * 256 + threadIdx.x;
    int d = idx & 2047;
    int r = idx >> 11;
    int l = r & 1023;

    float4 w4 = *(const float4*)(cw + 4 * d);
    float w[4] = { w4.x, w4.y, w4.z, w4.w };
    float acc = cb[d];
    const float* up = upre + (size_t)r * 2048 + d;
    if (l >= 3) {
        acc += w[0] * up[-3 * 2048] + w[1] * up[-2 * 2048]
             + w[2] * up[-1 * 2048] + w[3] * up[0];
    } else {
        #pragma unroll
        for (int j = 0; j < 4; ++j) {
            int lj = l - 3 + j;
            if (lj >= 0) acc += w[j] * up[(j - 3) * 2048];
        }
    }
    float sig = 1.f / (1.f + expf(-acc));
    uc[idx] = acc * sig;
}

// ---------------------------------------------------------------------------
// Register-state chunk-parallel scan (thread per (b,d,chunk), h[16] in VGPRs).
// ---------------------------------------------------------------------------
__global__ __launch_bounds__(256) void scan_pass1(
    const float* __restrict__ uc,
    const float* __restrict__ dtb,
    const float* __restrict__ xdbl,
    const float* __restrict__ A_log,
    float* __restrict__ Hend,         // [2][CF][2048][16]
    float* __restrict__ Sdt)          // [2][CF][2048]
{
    __shared__ float sB[CLEN][16];
    const int tid = threadIdx.x;
    const int bx  = blockIdx.x;
    const int c   = bx & (CF - 1);
    const int g   = (bx >> 5) & 7;
    const int b   = bx >> 8;
    const int d   = g * 256 + tid;
    const size_t rowbase = (size_t)b * 1024 + c * CLEN;

    for (int i = tid; i < CLEN * 16; i += 256) {
        int tt = i >> 4, nn = i & 15;
        sB[tt][nn] = xdbl[(rowbase + tt) * 96 + 64 + nn];
    }

    float A2[16];
    {
        float al[16];
        #pragma unroll
        for (int q = 0; q < 4; ++q)
            *(float4*)&al[4 * q] = *(const float4*)&A_log[(size_t)d * 16 + 4 * q];
        #pragma unroll
        for (int n = 0; n < 16; ++n) A2[n] = -expf(al[n]) * 1.44269504f;
    }
    __syncthreads();

    float h[16];
    #pragma unroll
    for (int n = 0; n < 16; ++n) h[n] = 0.f;
    float sdt = 0.f;

    #pragma unroll 4
    for (int t = 0; t < CLEN; ++t) {
        size_t r = rowbase + t;
        float dtv = dtb[r * 2048 + d];
        float uv  = uc [r * 2048 + d];
        sdt += dtv;
        float dtu = dtv * uv;
        float bl[16];
        #pragma unroll
        for (int q = 0; q < 4; ++q)
            *(float4*)&bl[4 * q] = *(const float4*)&sB[t][4 * q];
        #pragma unroll
        for (int n = 0; n < 16; ++n)
            h[n] = exp2f(dtv * A2[n]) * h[n] + dtu * bl[n];
    }

    size_t base = ((size_t)(b * CF + c) * 2048 + d) * 16;
    #pragma unroll
    for (int q = 0; q < 4; ++q)
        *(float4*)&Hend[base + 4 * q] = *(float4*)&h[4 * q];
    Sdt[(size_t)(b * CF + c) * 2048 + d] = sdt;
}

__global__ __launch_bounds__(256) void scan_pass2(
    const float* __restrict__ Hend, const float* __restrict__ Sdt,
    const float* __restrict__ A_log, float* __restrict__ Hin)
{
    int gid = blockIdx.x * 256 + threadIdx.x;   // 0..65535
    int b = gid >> 15;
    int rest = gid & 32767;                     // d*16+n
    int d = rest >> 4;
    float A2 = -expf(A_log[rest]) * 1.44269504f;
    float H = 0.f;
    #pragma unroll
    for (int c = 0; c < CF; ++c) {
        size_t sidx = (size_t)(b * CF + c) * 2048 + d;
        size_t idx  = ((size_t)(b * CF + c) << 15) + rest;
        Hin[idx] = H;
        H = exp2f(A2 * Sdt[sidx]) * H + Hend[idx];
    }
}

__global__ __launch_bounds__(256) void scan_pass3(
    const float* __restrict__ uc,
    const float* __restrict__ dtb,
    const unsigned short* __restrict__ zb,  // [2048][2048] bf16
    const float* __restrict__ xdbl,
    const float* __restrict__ A_log,
    const float* __restrict__ Dvec,
    const float* __restrict__ Hin,
    unsigned short* __restrict__ yb)
{
    __shared__ float sBC[CLEN][32];
    const int tid = threadIdx.x;
    const int bx  = blockIdx.x;
    const int c   = bx & (CF - 1);
    const int g   = (bx >> 5) & 7;
    const int b   = bx >> 8;
    const int d   = g * 256 + tid;
    const size_t rowbase = (size_t)b * 1024 + c * CLEN;

    for (int i = tid; i < CLEN * 32; i += 256) {
        int tt = i >> 5, j = i & 31;
        sBC[tt][j] = xdbl[(rowbase + tt) * 96 + 64 + j];
    }

    float A2[16];
    {
        float al[16];
        #pragma unroll
        for (int q = 0; q < 4; ++q)
            *(float4*)&al[4 * q] = *(const float4*)&A_log[(size_t)d * 16 + 4 * q];
        #pragma unroll
        for (int n = 0; n < 16; ++n) A2[n] = -expf(al[n]) * 1.44269504f;
    }
    const float Dd = Dvec[d];

    float h[16];
    {
        size_t base = ((size_t)(b * CF + c) * 2048 + d) * 16;
        #pragma unroll
        for (int q = 0; q < 4; ++q)
            *(float4*)&h[4 * q] = *(const float4*)&Hin[base + 4 * q];
    }
    __syncthreads();

    #pragma unroll 2
    for (int t = 0; t < CLEN; ++t) {
        size_t r = rowbase + t;
        float dtv = dtb[r * 2048 + d];
        float uv  = uc [r * 2048 + d];
        float zv  = bf2f(zb[r * 2048 + d]);
        float dtu = dtv * uv;
        float bl[16], cl[16];
        #pragma unroll
        for (int q = 0; q < 4; ++q) {
            *(float4*)&bl[4 * q] = *(const float4*)&sBC[t][4 * q];
            *(float4*)&cl[4 * q] = *(const float4*)&sBC[t][16 + 4 * q];
        }
        float acc = uv * Dd;
        #pragma unroll
        for (int n = 0; n < 16; ++n) {
            h[n] = exp2f(dtv * A2[n]) * h[n] + dtu * bl[n];
            acc += h[n] * cl[n];
        }
        float yv = acc * zv / (1.f + expf(-zv));
        yb[r * 2048 + d] = f2bf(yv);
    }
}

extern "C" void kernel_launch(void* const* d_in, const int* in_sizes, int n_in,
                              void* d_out, int out_size, void* d_ws, size_t ws_size,
                              hipStream_t stream)
{
    const float* x      = (const float*)d_in[0];
    const float* W_in   = (const float*)d_in[1];
    const float* conv_w = (const float*)d_in[2];
    const float* conv_b = (const float*)d_in[3];
    const float* W_x    = (const float*)d_in[4];
    const float* W_dt   = (const float*)d_in[5];
    const float* b_dt   = (const float*)d_in[6];
    const float* A_log  = (const float*)d_in[7];
    const float* Dv     = (const float*)d_in[8];
    const float* W_out  = (const float*)d_in[9];
    float* out = (float*)d_out;

    float* ws    = (float*)d_ws;
    float* upre  = ws;                       // [2048][2048] f32 (GEMM1 u half)
    float* dtb   = upre;                     // ALIAS: dt overwrites u_pre
    float* uc    = ws + 4194304;             // [2048][2048] f32
    float* xdbl  = uc + 4194304;             // [2048][96]   f32
    float* Hend  = xdbl + 196608;            // [2][CF][2048][16] = 2097152
    float* Hin   = Hend + 2097152;           // 2097152
    float* Sdt   = Hin + 2097152;            // [2][CF][2048] = 131072
    float* part  = Hend;                     // ALIAS: [16][2048][96] = 3145728
                                             //   (dead before pass1 writes Hend)
    unsigned short* zb   = (unsigned short*)(Sdt + 131072);  // [2048][2048] bf16
    unsigned short* xb   = zb + 4194304;     // [2048][1024] bf16
    unsigned short* wbT  = xb + 2097152;     // [4096][1024] bf16 (W_in^T)
    unsigned short* wobT = wbT + 4194304;    // [1024][2048] bf16 (W_out^T)
    unsigned short* yb   = wbT;              // aliases wbT (dead after GEMM1)

    dim3 blk(256);

    // prep
    transpose_cast<<<dim3(128, 32), blk, 0, stream>>>(W_in, wbT, 1024, 4096);
    transpose_cast<<<dim3(32, 64), blk, 0, stream>>>(W_out, wobT, 2048, 1024);
    cast_bf16<<<2048, blk, 0, stream>>>(x, xb);

    // 1. xz = x @ W_in   (bf16 MFMA; split epilogue: u fp32, z bf16)
    gemm_bf16<128><<<dim3(32, 16), blk, 0, stream>>>(
        xb, wbT, upre, zb, 1024, 1024, 1024, 0, 2048);

    // 2. u_c = silu(conv(u) + cb)
    conv_silu_kernel<<<(2048 * 2048) / 256, blk, 0, stream>>>(upre, conv_w, conv_b, uc);

    // 3. x_dbl = u_c @ W_x   (fp32 split-K, partials + reduce)
    gemm_f32_splitk<<<512, blk, 0, stream>>>(uc, W_x, part);
    reduce_splitk<<<192, blk, 0, stream>>>(part, xdbl);

    // 4. dt = softplus(x_dbl[:, :64] @ W_dt + b_dt)  (fp32; dtb aliases upre)
    gemm_f32<<<dim3(32, 32), blk, 0, stream>>>(
        xdbl, W_dt, dtb, 2048, 2048, 64, 96, 2048, 2048, 1, b_dt);

    // 5. register-state chunk scan
    scan_pass1<<<512, blk, 0, stream>>>(uc, dtb, xdbl, A_log, Hend, Sdt);
    scan_pass2<<<256, blk, 0, stream>>>(Hend, Sdt, A_log, Hin);
    scan_pass3<<<512, blk, 0, stream>>>(uc, dtb, zb, xdbl, A_log, Dv, Hin, yb);

    // 6. out = y @ W_out   (bf16 MFMA)
    gemm_bf16<64><<<dim3(8, 32), blk, 0, stream>>>(
        yb, wobT, out, nullptr, 2048, 2048, 2048, 1024, 0);
}

// Round 8
// 281.205 us; speedup vs baseline: 4.2348x; 1.0531x over previous
//
#include <hip/hip_runtime.h>
#include <hip/hip_bf16.h>

// ---------------------------------------------------------------------------
// Mamba block forward. Round 8: m97-style bf16 MFMA GEMM — BK=64,
// XOR-swizzled unpadded LDS (conflict-free ds_read_b128) and
// global_load_lds width-16 async staging. B=2 L=1024 DM=1024 DI=2048 DS=16
// ---------------------------------------------------------------------------

typedef __attribute__((ext_vector_type(8))) short bfrag;
typedef __attribute__((ext_vector_type(4))) float f32x4;

#define CF   32   // scan time-chunks
#define CLEN 32   // steps per chunk (CF*CLEN = 1024)

__device__ __forceinline__ unsigned short f2bf(float f) {
    unsigned int u = __float_as_uint(f);
    u += 0x7FFF + ((u >> 16) & 1);          // round-to-nearest-even
    return (unsigned short)(u >> 16);
}
__device__ __forceinline__ float bf2f(unsigned short s) {
    return __uint_as_float((unsigned int)s << 16);
}

__device__ __forceinline__ void async_copy16(const unsigned short* g,
                                             unsigned short* l) {
    // 16B per lane, direct global->LDS. LDS dest is wave-uniform base +
    // lane*16 (m104) — lane0's pointer is the chunk base.
    __builtin_amdgcn_global_load_lds(
        (const __attribute__((address_space(1))) void*)g,
        (__attribute__((address_space(3))) void*)l, 16, 0, 0);
}

// ---------------- bf16 MFMA GEMM v2: C[M][N] = A[M][K] * BT[N][K]^T ---------
// Tile MT x 128, BK=64, 4 waves (2x2). MT=128: wave 64x64; MT=64: wave 32x64.
// LDS layout: row-major [rows][64] shorts, k-block (8 shorts = 16B) at slot
// kblock ^ (row & 7)  -> ds_read_b128 frag reads are bank-conflict-free.
// Staging: each wave-instr fills 1KB (8 rows); lane l loads global k-block
// (l%8)^(l/8) of row chunk*8 + l/8, so LDS lands pre-swizzled.
// split>0: col<split -> fp32 C; col>=split -> bf16 C1 (both ld=split).
template<int MT>
__global__ __launch_bounds__(256) void gemm_bf16_v2(
    const unsigned short* __restrict__ A,   // [M][K] bf16
    const unsigned short* __restrict__ BT,  // [N][K] bf16
    float* __restrict__ C,
    unsigned short* __restrict__ C1,
    int K, int lda, int ldb, int ldc, int split)
{
    constexpr int FI  = MT / 32;            // 4 (MT=128) or 2 (MT=64)
    constexpr int ACH = MT / 32;            // A 1KB-chunks per wave
    __shared__ __align__(16) unsigned short sA[MT * 64];
    __shared__ __align__(16) unsigned short sB[128 * 64];

    const int tid  = threadIdx.x;
    const int wave = tid >> 6, lane = tid & 63;
    const int lm   = lane & 15;
    const int quad = lane >> 4;
    const int wrow = (wave >> 1) * (MT / 2);
    const int wcol = (wave & 1) * 64;
    const int bm = blockIdx.y * MT, bn = blockIdx.x * 128;

    const int lrow = lane >> 3;             // 0..7 (row within 8-row chunk)
    const int lkb  = (lane & 7) ^ lrow;     // swizzled k-block to fetch

    f32x4 acc[FI][4];
    #pragma unroll
    for (int i = 0; i < FI; ++i)
        #pragma unroll
        for (int j = 0; j < 4; ++j) {
            acc[i][j][0] = 0.f; acc[i][j][1] = 0.f;
            acc[i][j][2] = 0.f; acc[i][j][3] = 0.f;
        }

    for (int k0 = 0; k0 < K; k0 += 64) {
        // ---- async stage A (MT x 64) and B (128 x 64) ----
        #pragma unroll
        for (int c = 0; c < ACH; ++c) {
            const int chunk = wave * ACH + c;
            const int row = chunk * 8 + lrow;
            async_copy16(&A[(size_t)(bm + row) * lda + k0 + lkb * 8],
                         &sA[chunk * 512 + lane * 8]);
        }
        #pragma unroll
        for (int c = 0; c < 4; ++c) {
            const int chunk = wave * 4 + c;
            const int row = chunk * 8 + lrow;
            async_copy16(&BT[(size_t)(bn + row) * ldb + k0 + lkb * 8],
                         &sB[chunk * 512 + lane * 8]);
        }
        __syncthreads();   // drains vmcnt (global_load_lds) before ds_read

        #pragma unroll
        for (int ks = 0; ks < 2; ++ks) {
            bfrag af[FI], bf[4];
            #pragma unroll
            for (int i = 0; i < FI; ++i) {
                const int row = wrow + i * 16 + lm;
                const int slot = (ks * 4 + quad) ^ (row & 7);
                af[i] = *(const bfrag*)&sA[row * 64 + slot * 8];
            }
            #pragma unroll
            for (int j = 0; j < 4; ++j) {
                const int row = wcol + j * 16 + lm;
                const int slot = (ks * 4 + quad) ^ (row & 7);
                bf[j] = *(const bfrag*)&sB[row * 64 + slot * 8];
            }
            #pragma unroll
            for (int i = 0; i < FI; ++i)
                #pragma unroll
                for (int j = 0; j < 4; ++j)
                    acc[i][j] = __builtin_amdgcn_mfma_f32_16x16x32_bf16(
                        af[i], bf[j], acc[i][j], 0, 0, 0);
        }
        __syncthreads();
    }

    // C/D layout: col = lane&15, row = quad*4 + reg
    #pragma unroll
    for (int i = 0; i < FI; ++i)
        #pragma unroll
        for (int j = 0; j < 4; ++j) {
            const int col = bn + wcol + j * 16 + lm;
            #pragma unroll
            for (int r = 0; r < 4; ++r) {
                const int row = bm + wrow + i * 16 + quad * 4 + r;
                float v = acc[i][j][r];
                if (split > 0) {
                    if (col < split) C [(size_t)row * split + col] = v;
                    else             C1[(size_t)row * split + (col - split)] = f2bf(v);
                } else {
                    C[(size_t)row * ldc + col] = v;
                }
            }
        }
}

// ---------------- transpose + cast ------------------------------------------
__global__ __launch_bounds__(256) void transpose_cast(
    const float* __restrict__ in, unsigned short* __restrict__ out,
    int rows, int cols)
{
    __shared__ float tile[32][33];
    const int j0 = blockIdx.x * 32, i0 = blockIdx.y * 32;
    const int tx = threadIdx.x & 31, ty = threadIdx.x >> 5;
    #pragma unroll
    for (int k = 0; k < 4; ++k)
        tile[ty + 8 * k][tx] = in[(size_t)(i0 + ty + 8 * k) * cols + j0 + tx];
    __syncthreads();
    #pragma unroll
    for (int k = 0; k < 4; ++k)
        out[(size_t)(j0 + ty + 8 * k) * rows + i0 + tx] = f2bf(tile[tx][ty + 8 * k]);
}

__global__ __launch_bounds__(256) void cast_bf16(
    const float* __restrict__ in, unsigned short* __restrict__ out)
{
    int i = (blockIdx.x * 256 + threadIdx.x) * 4;
    float4 v = *(const float4*)&in[i];
    ushort4 o;
    o.x = f2bf(v.x); o.y = f2bf(v.y); o.z = f2bf(v.z); o.w = f2bf(v.w);
    *(ushort4*)&out[i] = o;
}

// ---------------- split-K fp32 GEMM: part[ks] = u_c @ W_x (K-slice) ---------
#define SK_KS 128
__global__ __launch_bounds__(256) void gemm_f32_splitk(
    const float* __restrict__ A, const float* __restrict__ B,
    float* __restrict__ part)                // [16][2048][96]
{
    __shared__ __align__(16) float As[16][64];
    __shared__ __align__(16) float Bs[16][96];

    const int tid = threadIdx.x;
    const int mtile = blockIdx.x >> 4;
    const int kslice = blockIdx.x & 15;
    const int bm = mtile * 64;
    const int kbase = kslice * SK_KS;

    const int am = tid >> 2;
    const int ak = (tid & 3) << 2;

    const int ty = tid >> 4, tx = tid & 15;
    const int rm = ty << 2;
    const int rn = tx * 6;

    float acc[4][6] = {};

    for (int k0 = 0; k0 < SK_KS; k0 += 16) {
        float4 av = *(const float4*)&A[(size_t)(bm + am) * 2048 + kbase + k0 + ak];
        As[ak + 0][am] = av.x;
        As[ak + 1][am] = av.y;
        As[ak + 2][am] = av.z;
        As[ak + 3][am] = av.w;
        for (int i = tid; i < 384; i += 256) {
            int br = i / 24, bc = (i % 24) << 2;
            *(float4*)&Bs[br][bc] = *(const float4*)&B[(size_t)(kbase + k0 + br) * 96 + bc];
        }
        __syncthreads();

        #pragma unroll
        for (int k = 0; k < 16; ++k) {
            float4 a = *(const float4*)&As[k][rm];
            float b[6];
            #pragma unroll
            for (int j = 0; j < 6; ++j) b[j] = Bs[k][rn + j];
            #pragma unroll
            for (int j = 0; j < 6; ++j) {
                acc[0][j] += a.x * b[j];
                acc[1][j] += a.y * b[j];
                acc[2][j] += a.z * b[j];
                acc[3][j] += a.w * b[j];
            }
        }
        __syncthreads();
    }

    float* pout = part + (size_t)kslice * 196608;
    #pragma unroll
    for (int i = 0; i < 4; ++i) {
        float* crow = pout + (size_t)(bm + rm + i) * 96 + rn;
        #pragma unroll
        for (int j = 0; j < 6; ++j)
            crow[j] = acc[i][j];
    }
}

// ---------------- reduce 16 split-K partials -> xdbl ------------------------
__global__ __launch_bounds__(256) void reduce_splitk(
    const float* __restrict__ part, float* __restrict__ xdbl)
{
    int i = (blockIdx.x * 256 + threadIdx.x) * 4;   // < 196608
    float4 acc = {0.f, 0.f, 0.f, 0.f};
    #pragma unroll
    for (int s = 0; s < 16; ++s) {
        float4 v = *(const float4*)&part[(size_t)s * 196608 + i];
        acc.x += v.x; acc.y += v.y; acc.z += v.z; acc.w += v.w;
    }
    *(float4*)&xdbl[i] = acc;
}

// ---------------- fp32 tiled GEMM (dt GEMM) ---------------------------------
#define BM 64
#define BN 64
#define BK 16
__global__ __launch_bounds__(256) void gemm_f32(
    const float* __restrict__ A, const float* __restrict__ B,
    float* __restrict__ C, int M, int N, int K,
    int lda, int ldb, int ldc, int mode, const float* __restrict__ bias)
{
    __shared__ __align__(16) float As[BK][BM];
    __shared__ __align__(16) float Bs[BK][BN];

    const int tid = threadIdx.x;
    const int bm = blockIdx.y * BM;
    const int bn = blockIdx.x * BN;

    const int am = tid >> 2;
    const int ak = (tid & 3) << 2;
    const int bk = tid >> 4;
    const int bnn = (tid & 15) << 2;

    const int tx = tid & 15, ty = tid >> 4;
    const int rm = ty << 2;
    const int rn = tx << 2;
    const int cm = bm + rm, cn = bn + rn;

    float acc[4][4] = {};

    for (int k0 = 0; k0 < K; k0 += BK) {
        const float* ap = A + (size_t)(bm + am) * lda + (k0 + ak);
        float4 av = *(const float4*)ap;
        As[ak + 0][am] = av.x;
        As[ak + 1][am] = av.y;
        As[ak + 2][am] = av.z;
        As[ak + 3][am] = av.w;
        {
            const int ncol = bn + bnn;
            const float* bp = B + (size_t)(k0 + bk) * ldb + ncol;
            float4 bv;
            if (ncol + 3 < N) {
                bv = *(const float4*)bp;
            } else {
                bv.x = (ncol + 0 < N) ? bp[0] : 0.f;
                bv.y = (ncol + 1 < N) ? bp[1] : 0.f;
                bv.z = (ncol + 2 < N) ? bp[2] : 0.f;
                bv.w = (ncol + 3 < N) ? bp[3] : 0.f;
            }
            *(float4*)&Bs[bk][bnn] = bv;
        }
        __syncthreads();

        #pragma unroll
        for (int k = 0; k < BK; ++k) {
            float4 a = *(const float4*)&As[k][rm];
            float4 b = *(const float4*)&Bs[k][rn];
            acc[0][0] += a.x * b.x; acc[0][1] += a.x * b.y;
            acc[0][2] += a.x * b.z; acc[0][3] += a.x * b.w;
            acc[1][0] += a.y * b.x; acc[1][1] += a.y * b.y;
            acc[1][2] += a.y * b.z; acc[1][3] += a.y * b.w;
            acc[2][0] += a.z * b.x; acc[2][1] += a.z * b.y;
            acc[2][2] += a.z * b.z; acc[2][3] += a.z * b.w;
            acc[3][0] += a.w * b.x; acc[3][1] += a.w * b.y;
            acc[3][2] += a.w * b.z; acc[3][3] += a.w * b.w;
        }
        __syncthreads();
    }

    #pragma unroll
    for (int i = 0; i < 4; ++i) {
        float* crow = C + (size_t)(cm + i) * ldc;
        #pragma unroll
        for (int j = 0; j < 4; ++j) {
            int col = cn + j;
            if (col < N) {
                float v = acc[i][j];
                if (mode == 1) {
                    v += bias[col];
                    v = (v > 20.f) ? v : logf(1.f + expf(v));  // softplus
                }
                crow[col] = v;
            }
        }
    }
}

// ---------------- depthwise causal conv(4) + bias + SiLU --------------------
__global__ __launch_bounds__(256) void conv_silu_kernel(
    const float* __restrict__ upre, const float* __restrict__ cw,
    const float* __restrict__ cb, float* __restrict__ uc)
{
    int idx = blockIdx.x * 256 + threadIdx.x;
    int d = idx & 2047;
    int r = idx >> 11;
    int l = r & 1023;

    float4 w4 = *(const float4*)(cw + 4 * d);
    float w[4] = { w4.x, w4.y, w4.z, w4.w };
    float acc = cb[d];
    const float* up = upre + (size_t)r * 2048 + d;
    if (l >= 3) {
        acc += w[0] * up[-3 * 2048] + w[1] * up[-2 * 2048]
             + w[2] * up[-1 * 2048] + w[3] * up[0];
    } else {
        #pragma unroll
        for (int j = 0; j < 4; ++j) {
            int lj = l - 3 + j;
            if (lj >= 0) acc += w[j] * up[(j - 3) * 2048];
        }
    }
    float sig = 1.f / (1.f + expf(-acc));
    uc[idx] = acc * sig;
}

// ---------------------------------------------------------------------------
// Register-state chunk-parallel scan (thread per (b,d,chunk), h[16] in VGPRs).
// ---------------------------------------------------------------------------
__global__ __launch_bounds__(256) void scan_pass1(
    const float* __restrict__ uc,
    const float* __restrict__ dtb,
    const float* __restrict__ xdbl,
    const float* __restrict__ A_log,
    float* __restrict__ Hend,         // [2][CF][2048][16]
    float* __restrict__ Sdt)          // [2][CF][2048]
{
    __shared__ float sB[CLEN][16];
    const int tid = threadIdx.x;
    const int bx  = blockIdx.x;
    const int c   = bx & (CF - 1);
    const int g   = (bx >> 5) & 7;
    const int b   = bx >> 8;
    const int d   = g * 256 + tid;
    const size_t rowbase = (size_t)b * 1024 + c * CLEN;

    for (int i = tid; i < CLEN * 16; i += 256) {
        int tt = i >> 4, nn = i & 15;
        sB[tt][nn] = xdbl[(rowbase + tt) * 96 + 64 + nn];
    }

    float A2[16];
    {
        float al[16];
        #pragma unroll
        for (int q = 0; q < 4; ++q)
            *(float4*)&al[4 * q] = *(const float4*)&A_log[(size_t)d * 16 + 4 * q];
        #pragma unroll
        for (int n = 0; n < 16; ++n) A2[n] = -expf(al[n]) * 1.44269504f;
    }
    __syncthreads();

    float h[16];
    #pragma unroll
    for (int n = 0; n < 16; ++n) h[n] = 0.f;
    float sdt = 0.f;

    #pragma unroll 4
    for (int t = 0; t < CLEN; ++t) {
        size_t r = rowbase + t;
        float dtv = dtb[r * 2048 + d];
        float uv  = uc [r * 2048 + d];
        sdt += dtv;
        float dtu = dtv * uv;
        float bl[16];
        #pragma unroll
        for (int q = 0; q < 4; ++q)
            *(float4*)&bl[4 * q] = *(const float4*)&sB[t][4 * q];
        #pragma unroll
        for (int n = 0; n < 16; ++n)
            h[n] = exp2f(dtv * A2[n]) * h[n] + dtu * bl[n];
    }

    size_t base = ((size_t)(b * CF + c) * 2048 + d) * 16;
    #pragma unroll
    for (int q = 0; q < 4; ++q)
        *(float4*)&Hend[base + 4 * q] = *(float4*)&h[4 * q];
    Sdt[(size_t)(b * CF + c) * 2048 + d] = sdt;
}

__global__ __launch_bounds__(256) void scan_pass2(
    const float* __restrict__ Hend, const float* __restrict__ Sdt,
    const float* __restrict__ A_log, float* __restrict__ Hin)
{
    int gid = blockIdx.x * 256 + threadIdx.x;   // 0..65535
    int b = gid >> 15;
    int rest = gid & 32767;                     // d*16+n
    int d = rest >> 4;
    float A2 = -expf(A_log[rest]) * 1.44269504f;
    float H = 0.f;
    #pragma unroll
    for (int c = 0; c < CF; ++c) {
        size_t sidx = (size_t)(b * CF + c) * 2048 + d;
        size_t idx  = ((size_t)(b * CF + c) << 15) + rest;
        Hin[idx] = H;
        H = exp2f(A2 * Sdt[sidx]) * H + Hend[idx];
    }
}

__global__ __launch_bounds__(256) void scan_pass3(
    const float* __restrict__ uc,
    const float* __restrict__ dtb,
    const unsigned short* __restrict__ zb,  // [2048][2048] bf16
    const float* __restrict__ xdbl,
    const float* __restrict__ A_log,
    const float* __restrict__ Dvec,
    const float* __restrict__ Hin,
    unsigned short* __restrict__ yb)
{
    __shared__ float sBC[CLEN][32];
    const int tid = threadIdx.x;
    const int bx  = blockIdx.x;
    const int c   = bx & (CF - 1);
    const int g   = (bx >> 5) & 7;
    const int b   = bx >> 8;
    const int d   = g * 256 + tid;
    const size_t rowbase = (size_t)b * 1024 + c * CLEN;

    for (int i = tid; i < CLEN * 32; i += 256) {
        int tt = i >> 5, j = i & 31;
        sBC[tt][j] = xdbl[(rowbase + tt) * 96 + 64 + j];
    }

    float A2[16];
    {
        float al[16];
        #pragma unroll
        for (int q = 0; q < 4; ++q)
            *(float4*)&al[4 * q] = *(const float4*)&A_log[(size_t)d * 16 + 4 * q];
        #pragma unroll
        for (int n = 0; n < 16; ++n) A2[n] = -expf(al[n]) * 1.44269504f;
    }
    const float Dd = Dvec[d];

    float h[16];
    {
        size_t base = ((size_t)(b * CF + c) * 2048 + d) * 16;
        #pragma unroll
        for (int q = 0; q < 4; ++q)
            *(float4*)&h[4 * q] = *(const float4*)&Hin[base + 4 * q];
    }
    __syncthreads();

    #pragma unroll 2
    for (int t = 0; t < CLEN; ++t) {
        size_t r = rowbase + t;
        float dtv = dtb[r * 2048 + d];
        float uv  = uc [r * 2048 + d];
        float zv  = bf2f(zb[r * 2048 + d]);
        float dtu = dtv * uv;
        float bl[16], cl[16];
        #pragma unroll
        for (int q = 0; q < 4; ++q) {
            *(float4*)&bl[4 * q] = *(const float4*)&sBC[t][4 * q];
            *(float4*)&cl[4 * q] = *(const float4*)&sBC[t][16 + 4 * q];
        }
        float acc = uv * Dd;
        #pragma unroll
        for (int n = 0; n < 16; ++n) {
            h[n] = exp2f(dtv * A2[n]) * h[n] + dtu * bl[n];
            acc += h[n] * cl[n];
        }
        float yv = acc * zv / (1.f + expf(-zv));
        yb[r * 2048 + d] = f2bf(yv);
    }
}

extern "C" void kernel_launch(void* const* d_in, const int* in_sizes, int n_in,
                              void* d_out, int out_size, void* d_ws, size_t ws_size,
                              hipStream_t stream)
{
    const float* x      = (const float*)d_in[0];
    const float* W_in   = (const float*)d_in[1];
    const float* conv_w = (const float*)d_in[2];
    const float* conv_b = (const float*)d_in[3];
    const float* W_x    = (const float*)d_in[4];
    const float* W_dt   = (const float*)d_in[5];
    const float* b_dt   = (const float*)d_in[6];
    const float* A_log  = (const float*)d_in[7];
    const float* Dv     = (const float*)d_in[8];
    const float* W_out  = (const float*)d_in[9];
    float* out = (float*)d_out;

    float* ws    = (float*)d_ws;
    float* upre  = ws;                       // [2048][2048] f32 (GEMM1 u half)
    float* dtb   = upre;                     // ALIAS: dt overwrites u_pre
    float* uc    = ws + 4194304;             // [2048][2048] f32
    float* xdbl  = uc + 4194304;             // [2048][96]   f32
    float* Hend  = xdbl + 196608;            // [2][CF][2048][16] = 2097152
    float* Hin   = Hend + 2097152;           // 2097152
    float* Sdt   = Hin + 2097152;            // [2][CF][2048] = 131072
    float* part  = Hend;                     // ALIAS: [16][2048][96] = 3145728
                                             //   (dead before pass1 writes Hend)
    unsigned short* zb   = (unsigned short*)(Sdt + 131072);  // [2048][2048] bf16
    unsigned short* xb   = zb + 4194304;     // [2048][1024] bf16
    unsigned short* wbT  = xb + 2097152;     // [4096][1024] bf16 (W_in^T)
    unsigned short* wobT = wbT + 4194304;    // [1024][2048] bf16 (W_out^T)
    unsigned short* yb   = wbT;              // aliases wbT (dead after GEMM1)

    dim3 blk(256);

    // prep
    transpose_cast<<<dim3(128, 32), blk, 0, stream>>>(W_in, wbT, 1024, 4096);
    transpose_cast<<<dim3(32, 64), blk, 0, stream>>>(W_out, wobT, 2048, 1024);
    cast_bf16<<<2048, blk, 0, stream>>>(x, xb);

    // 1. xz = x @ W_in   (bf16 MFMA v2; split epilogue: u fp32, z bf16)
    gemm_bf16_v2<128><<<dim3(32, 16), blk, 0, stream>>>(
        xb, wbT, upre, zb, 1024, 1024, 1024, 0, 2048);

    // 2. u_c = silu(conv(u) + cb)
    conv_silu_kernel<<<(2048 * 2048) / 256, blk, 0, stream>>>(upre, conv_w, conv_b, uc);

    // 3. x_dbl = u_c @ W_x   (fp32 split-K, partials + reduce)
    gemm_f32_splitk<<<512, blk, 0, stream>>>(uc, W_x, part);
    reduce_splitk<<<192, blk, 0, stream>>>(part, xdbl);

    // 4. dt = softplus(x_dbl[:, :64] @ W_dt + b_dt)  (fp32; dtb aliases upre)
    gemm_f32<<<dim3(32, 32), blk, 0, stream>>>(
        xdbl, W_dt, dtb, 2048, 2048, 64, 96, 2048, 2048, 1, b_dt);

    // 5. register-state chunk scan
    scan_pass1<<<512, blk, 0, stream>>>(uc, dtb, xdbl, A_log, Hend, Sdt);
    scan_pass2<<<256, blk, 0, stream>>>(Hend, Sdt, A_log, Hin);
    scan_pass3<<<512, blk, 0, stream>>>(uc, dtb, zb, xdbl, A_log, Dv, Hin, yb);

    // 6. out = y @ W_out   (bf16 MFMA v2, 64x128 tile -> 256 blocks)
    gemm_bf16_v2<64><<<dim3(8, 32), blk, 0, stream>>>(
        yb, wobT, out, nullptr, 2048, 2048, 2048, 1024, 0);
}

// Round 9
// 271.759 us; speedup vs baseline: 4.3820x; 1.0348x over previous
//
#include <hip/hip_runtime.h>
#include <hip/hip_bf16.h>

// ---------------------------------------------------------------------------
// Mamba block forward. Round 9: bf16 intermediates (uc, dt) to cut ~56MB of
// HBM traffic; GEMM6 retiled to 64x64 (512 blocks, 2/CU).
// B=2 L=1024 DM=1024 DI=2048 DS=16 DTR=64
// ---------------------------------------------------------------------------

typedef __attribute__((ext_vector_type(8))) short bfrag;
typedef __attribute__((ext_vector_type(4))) float f32x4;

#define CF   32   // scan time-chunks
#define CLEN 32   // steps per chunk (CF*CLEN = 1024)

__device__ __forceinline__ unsigned short f2bf(float f) {
    unsigned int u = __float_as_uint(f);
    u += 0x7FFF + ((u >> 16) & 1);          // round-to-nearest-even
    return (unsigned short)(u >> 16);
}
__device__ __forceinline__ float bf2f(unsigned short s) {
    return __uint_as_float((unsigned int)s << 16);
}

__device__ __forceinline__ void async_copy16(const unsigned short* g,
                                             unsigned short* l) {
    __builtin_amdgcn_global_load_lds(
        (const __attribute__((address_space(1))) void*)g,
        (__attribute__((address_space(3))) void*)l, 16, 0, 0);
}

// ---------------- bf16 MFMA GEMM v2: C[M][N] = A[M][K] * BT[N][K]^T ---------
// Tile MT x NT, BK=64, 4 waves (2x2), wave does (MT/2)x(NT/2).
// XOR-swizzled unpadded LDS; global_load_lds width-16 staging.
// split>0: col<split -> fp32 C; col>=split -> bf16 C1 (both ld=split).
template<int MT, int NT>
__global__ __launch_bounds__(256) void gemm_bf16_v2(
    const unsigned short* __restrict__ A,   // [M][K] bf16
    const unsigned short* __restrict__ BT,  // [N][K] bf16
    float* __restrict__ C,
    unsigned short* __restrict__ C1,
    int K, int lda, int ldb, int ldc, int split)
{
    constexpr int FI  = MT / 32;
    constexpr int FJ  = NT / 32;
    constexpr int ACH = MT / 32;            // A 1KB-chunks per wave
    constexpr int BCH = NT / 32;
    __shared__ __align__(16) unsigned short sA[MT * 64];
    __shared__ __align__(16) unsigned short sB[NT * 64];

    const int tid  = threadIdx.x;
    const int wave = tid >> 6, lane = tid & 63;
    const int lm   = lane & 15;
    const int quad = lane >> 4;
    const int wrow = (wave >> 1) * (MT / 2);
    const int wcol = (wave & 1) * (NT / 2);
    const int bm = blockIdx.y * MT, bn = blockIdx.x * NT;

    const int lrow = lane >> 3;             // 0..7 (row within 8-row chunk)
    const int lkb  = (lane & 7) ^ lrow;     // swizzled k-block to fetch

    f32x4 acc[FI][FJ];
    #pragma unroll
    for (int i = 0; i < FI; ++i)
        #pragma unroll
        for (int j = 0; j < FJ; ++j) {
            acc[i][j][0] = 0.f; acc[i][j][1] = 0.f;
            acc[i][j][2] = 0.f; acc[i][j][3] = 0.f;
        }

    for (int k0 = 0; k0 < K; k0 += 64) {
        #pragma unroll
        for (int c = 0; c < ACH; ++c) {
            const int chunk = wave * ACH + c;
            const int row = chunk * 8 + lrow;
            async_copy16(&A[(size_t)(bm + row) * lda + k0 + lkb * 8],
                         &sA[chunk * 512 + lane * 8]);
        }
        #pragma unroll
        for (int c = 0; c < BCH; ++c) {
            const int chunk = wave * BCH + c;
            const int row = chunk * 8 + lrow;
            async_copy16(&BT[(size_t)(bn + row) * ldb + k0 + lkb * 8],
                         &sB[chunk * 512 + lane * 8]);
        }
        __syncthreads();

        #pragma unroll
        for (int ks = 0; ks < 2; ++ks) {
            bfrag af[FI], bf[FJ];
            #pragma unroll
            for (int i = 0; i < FI; ++i) {
                const int row = wrow + i * 16 + lm;
                const int slot = (ks * 4 + quad) ^ (row & 7);
                af[i] = *(const bfrag*)&sA[row * 64 + slot * 8];
            }
            #pragma unroll
            for (int j = 0; j < FJ; ++j) {
                const int row = wcol + j * 16 + lm;
                const int slot = (ks * 4 + quad) ^ (row & 7);
                bf[j] = *(const bfrag*)&sB[row * 64 + slot * 8];
            }
            #pragma unroll
            for (int i = 0; i < FI; ++i)
                #pragma unroll
                for (int j = 0; j < FJ; ++j)
                    acc[i][j] = __builtin_amdgcn_mfma_f32_16x16x32_bf16(
                        af[i], bf[j], acc[i][j], 0, 0, 0);
        }
        __syncthreads();
    }

    // C/D layout: col = lane&15, row = quad*4 + reg
    #pragma unroll
    for (int i = 0; i < FI; ++i)
        #pragma unroll
        for (int j = 0; j < FJ; ++j) {
            const int col = bn + wcol + j * 16 + lm;
            #pragma unroll
            for (int r = 0; r < 4; ++r) {
                const int row = bm + wrow + i * 16 + quad * 4 + r;
                float v = acc[i][j][r];
                if (split > 0) {
                    if (col < split) C [(size_t)row * split + col] = v;
                    else             C1[(size_t)row * split + (col - split)] = f2bf(v);
                } else {
                    C[(size_t)row * ldc + col] = v;
                }
            }
        }
}

// ---------------- transpose + cast ------------------------------------------
__global__ __launch_bounds__(256) void transpose_cast(
    const float* __restrict__ in, unsigned short* __restrict__ out,
    int rows, int cols)
{
    __shared__ float tile[32][33];
    const int j0 = blockIdx.x * 32, i0 = blockIdx.y * 32;
    const int tx = threadIdx.x & 31, ty = threadIdx.x >> 5;
    #pragma unroll
    for (int k = 0; k < 4; ++k)
        tile[ty + 8 * k][tx] = in[(size_t)(i0 + ty + 8 * k) * cols + j0 + tx];
    __syncthreads();
    #pragma unroll
    for (int k = 0; k < 4; ++k)
        out[(size_t)(j0 + ty + 8 * k) * rows + i0 + tx] = f2bf(tile[tx][ty + 8 * k]);
}

__global__ __launch_bounds__(256) void cast_bf16(
    const float* __restrict__ in, unsigned short* __restrict__ out)
{
    int i = (blockIdx.x * 256 + threadIdx.x) * 4;
    float4 v = *(const float4*)&in[i];
    ushort4 o;
    o.x = f2bf(v.x); o.y = f2bf(v.y); o.z = f2bf(v.z); o.w = f2bf(v.w);
    *(ushort4*)&out[i] = o;
}

// ---------------- split-K fp32 GEMM: part[ks] = u_c @ W_x (A is bf16) -------
#define SK_KS 128
__global__ __launch_bounds__(256) void gemm_f32_splitk(
    const unsigned short* __restrict__ A,    // [2048][2048] bf16
    const float* __restrict__ B,
    float* __restrict__ part)                // [16][2048][96]
{
    __shared__ __align__(16) float As[16][64];
    __shared__ __align__(16) float Bs[16][96];

    const int tid = threadIdx.x;
    const int mtile = blockIdx.x >> 4;
    const int kslice = blockIdx.x & 15;
    const int bm = mtile * 64;
    const int kbase = kslice * SK_KS;

    const int am = tid >> 2;
    const int ak = (tid & 3) << 2;

    const int ty = tid >> 4, tx = tid & 15;
    const int rm = ty << 2;
    const int rn = tx * 6;

    float acc[4][6] = {};

    for (int k0 = 0; k0 < SK_KS; k0 += 16) {
        ushort4 av = *(const ushort4*)&A[(size_t)(bm + am) * 2048 + kbase + k0 + ak];
        As[ak + 0][am] = bf2f(av.x);
        As[ak + 1][am] = bf2f(av.y);
        As[ak + 2][am] = bf2f(av.z);
        As[ak + 3][am] = bf2f(av.w);
        for (int i = tid; i < 384; i += 256) {
            int br = i / 24, bc = (i % 24) << 2;
            *(float4*)&Bs[br][bc] = *(const float4*)&B[(size_t)(kbase + k0 + br) * 96 + bc];
        }
        __syncthreads();

        #pragma unroll
        for (int k = 0; k < 16; ++k) {
            float4 a = *(const float4*)&As[k][rm];
            float b[6];
            #pragma unroll
            for (int j = 0; j < 6; ++j) b[j] = Bs[k][rn + j];
            #pragma unroll
            for (int j = 0; j < 6; ++j) {
                acc[0][j] += a.x * b[j];
                acc[1][j] += a.y * b[j];
                acc[2][j] += a.z * b[j];
                acc[3][j] += a.w * b[j];
            }
        }
        __syncthreads();
    }

    float* pout = part + (size_t)kslice * 196608;
    #pragma unroll
    for (int i = 0; i < 4; ++i) {
        float* crow = pout + (size_t)(bm + rm + i) * 96 + rn;
        #pragma unroll
        for (int j = 0; j < 6; ++j)
            crow[j] = acc[i][j];
    }
}

// ---------------- reduce 16 split-K partials -> xdbl ------------------------
__global__ __launch_bounds__(256) void reduce_splitk(
    const float* __restrict__ part, float* __restrict__ xdbl)
{
    int i = (blockIdx.x * 256 + threadIdx.x) * 4;   // < 196608
    float4 acc = {0.f, 0.f, 0.f, 0.f};
    #pragma unroll
    for (int s = 0; s < 16; ++s) {
        float4 v = *(const float4*)&part[(size_t)s * 196608 + i];
        acc.x += v.x; acc.y += v.y; acc.z += v.z; acc.w += v.w;
    }
    *(float4*)&xdbl[i] = acc;
}

// ---------------- fp32 tiled GEMM (dt GEMM; mode==1 -> bf16 out) ------------
#define BM 64
#define BN 64
#define BK 16
__global__ __launch_bounds__(256) void gemm_f32(
    const float* __restrict__ A, const float* __restrict__ B,
    float* __restrict__ C, int M, int N, int K,
    int lda, int ldb, int ldc, int mode, const float* __restrict__ bias)
{
    __shared__ __align__(16) float As[BK][BM];
    __shared__ __align__(16) float Bs[BK][BN];

    const int tid = threadIdx.x;
    const int bm = blockIdx.y * BM;
    const int bn = blockIdx.x * BN;

    const int am = tid >> 2;
    const int ak = (tid & 3) << 2;
    const int bk = tid >> 4;
    const int bnn = (tid & 15) << 2;

    const int tx = tid & 15, ty = tid >> 4;
    const int rm = ty << 2;
    const int rn = tx << 2;
    const int cm = bm + rm, cn = bn + rn;

    float acc[4][4] = {};

    for (int k0 = 0; k0 < K; k0 += BK) {
        const float* ap = A + (size_t)(bm + am) * lda + (k0 + ak);
        float4 av = *(const float4*)ap;
        As[ak + 0][am] = av.x;
        As[ak + 1][am] = av.y;
        As[ak + 2][am] = av.z;
        As[ak + 3][am] = av.w;
        {
            const int ncol = bn + bnn;
            const float* bp = B + (size_t)(k0 + bk) * ldb + ncol;
            float4 bv;
            if (ncol + 3 < N) {
                bv = *(const float4*)bp;
            } else {
                bv.x = (ncol + 0 < N) ? bp[0] : 0.f;
                bv.y = (ncol + 1 < N) ? bp[1] : 0.f;
                bv.z = (ncol + 2 < N) ? bp[2] : 0.f;
                bv.w = (ncol + 3 < N) ? bp[3] : 0.f;
            }
            *(float4*)&Bs[bk][bnn] = bv;
        }
        __syncthreads();

        #pragma unroll
        for (int k = 0; k < BK; ++k) {
            float4 a = *(const float4*)&As[k][rm];
            float4 b = *(const float4*)&Bs[k][rn];
            acc[0][0] += a.x * b.x; acc[0][1] += a.x * b.y;
            acc[0][2] += a.x * b.z; acc[0][3] += a.x * b.w;
            acc[1][0] += a.y * b.x; acc[1][1] += a.y * b.y;
            acc[1][2] += a.y * b.z; acc[1][3] += a.y * b.w;
            acc[2][0] += a.z * b.x; acc[2][1] += a.z * b.y;
            acc[2][2] += a.z * b.z; acc[2][3] += a.z * b.w;
            acc[3][0] += a.w * b.x; acc[3][1] += a.w * b.y;
            acc[3][2] += a.w * b.z; acc[3][3] += a.w * b.w;
        }
        __syncthreads();
    }

    #pragma unroll
    for (int i = 0; i < 4; ++i) {
        #pragma unroll
        for (int j = 0; j < 4; ++j) {
            int col = cn + j;
            if (col < N) {
                float v = acc[i][j];
                if (mode == 1) {
                    v += bias[col];
                    v = (v > 20.f) ? v : logf(1.f + expf(v));  // softplus
                    ((unsigned short*)C)[(size_t)(cm + i) * ldc + col] = f2bf(v);
                } else {
                    C[(size_t)(cm + i) * ldc + col] = v;
                }
            }
        }
    }
}

// ---------------- depthwise causal conv(4) + bias + SiLU -> bf16 ------------
__global__ __launch_bounds__(256) void conv_silu_kernel(
    const float* __restrict__ upre, const float* __restrict__ cw,
    const float* __restrict__ cb, unsigned short* __restrict__ uc)
{
    int idx = blockIdx.x * 256 + threadIdx.x;
    int d = idx & 2047;
    int r = idx >> 11;
    int l = r & 1023;

    float4 w4 = *(const float4*)(cw + 4 * d);
    float w[4] = { w4.x, w4.y, w4.z, w4.w };
    float acc = cb[d];
    const float* up = upre + (size_t)r * 2048 + d;
    if (l >= 3) {
        acc += w[0] * up[-3 * 2048] + w[1] * up[-2 * 2048]
             + w[2] * up[-1 * 2048] + w[3] * up[0];
    } else {
        #pragma unroll
        for (int j = 0; j < 4; ++j) {
            int lj = l - 3 + j;
            if (lj >= 0) acc += w[j] * up[(j - 3) * 2048];
        }
    }
    float sig = 1.f / (1.f + expf(-acc));
    uc[idx] = f2bf(acc * sig);
}

// ---------------------------------------------------------------------------
// Register-state chunk-parallel scan (thread per (b,d,chunk), h[16] in VGPRs).
// uc and dt are bf16.
// ---------------------------------------------------------------------------
__global__ __launch_bounds__(256) void scan_pass1(
    const unsigned short* __restrict__ uc,
    const unsigned short* __restrict__ dtb,
    const float* __restrict__ xdbl,
    const float* __restrict__ A_log,
    float* __restrict__ Hend,         // [2][CF][2048][16]
    float* __restrict__ Sdt)          // [2][CF][2048]
{
    __shared__ float sB[CLEN][16];
    const int tid = threadIdx.x;
    const int bx  = blockIdx.x;
    const int c   = bx & (CF - 1);
    const int g   = (bx >> 5) & 7;
    const int b   = bx >> 8;
    const int d   = g * 256 + tid;
    const size_t rowbase = (size_t)b * 1024 + c * CLEN;

    for (int i = tid; i < CLEN * 16; i += 256) {
        int tt = i >> 4, nn = i & 15;
        sB[tt][nn] = xdbl[(rowbase + tt) * 96 + 64 + nn];
    }

    float A2[16];
    {
        float al[16];
        #pragma unroll
        for (int q = 0; q < 4; ++q)
            *(float4*)&al[4 * q] = *(const float4*)&A_log[(size_t)d * 16 + 4 * q];
        #pragma unroll
        for (int n = 0; n < 16; ++n) A2[n] = -expf(al[n]) * 1.44269504f;
    }
    __syncthreads();

    float h[16];
    #pragma unroll
    for (int n = 0; n < 16; ++n) h[n] = 0.f;
    float sdt = 0.f;

    #pragma unroll 4
    for (int t = 0; t < CLEN; ++t) {
        size_t r = rowbase + t;
        float dtv = bf2f(dtb[r * 2048 + d]);
        float uv  = bf2f(uc [r * 2048 + d]);
        sdt += dtv;
        float dtu = dtv * uv;
        float bl[16];
        #pragma unroll
        for (int q = 0; q < 4; ++q)
            *(float4*)&bl[4 * q] = *(const float4*)&sB[t][4 * q];
        #pragma unroll
        for (int n = 0; n < 16; ++n)
            h[n] = exp2f(dtv * A2[n]) * h[n] + dtu * bl[n];
    }

    size_t base = ((size_t)(b * CF + c) * 2048 + d) * 16;
    #pragma unroll
    for (int q = 0; q < 4; ++q)
        *(float4*)&Hend[base + 4 * q] = *(float4*)&h[4 * q];
    Sdt[(size_t)(b * CF + c) * 2048 + d] = sdt;
}

__global__ __launch_bounds__(256) void scan_pass2(
    const float* __restrict__ Hend, const float* __restrict__ Sdt,
    const float* __restrict__ A_log, float* __restrict__ Hin)
{
    int gid = blockIdx.x * 256 + threadIdx.x;   // 0..65535
    int b = gid >> 15;
    int rest = gid & 32767;                     // d*16+n
    int d = rest >> 4;
    float A2 = -expf(A_log[rest]) * 1.44269504f;
    float H = 0.f;
    #pragma unroll
    for (int c = 0; c < CF; ++c) {
        size_t sidx = (size_t)(b * CF + c) * 2048 + d;
        size_t idx  = ((size_t)(b * CF + c) << 15) + rest;
        Hin[idx] = H;
        H = exp2f(A2 * Sdt[sidx]) * H + Hend[idx];
    }
}

__global__ __launch_bounds__(256) void scan_pass3(
    const unsigned short* __restrict__ uc,
    const unsigned short* __restrict__ dtb,
    const unsigned short* __restrict__ zb,  // [2048][2048] bf16
    const float* __restrict__ xdbl,
    const float* __restrict__ A_log,
    const float* __restrict__ Dvec,
    const float* __restrict__ Hin,
    unsigned short* __restrict__ yb)
{
    __shared__ float sBC[CLEN][32];
    const int tid = threadIdx.x;
    const int bx  = blockIdx.x;
    const int c   = bx & (CF - 1);
    const int g   = (bx >> 5) & 7;
    const int b   = bx >> 8;
    const int d   = g * 256 + tid;
    const size_t rowbase = (size_t)b * 1024 + c * CLEN;

    for (int i = tid; i < CLEN * 32; i += 256) {
        int tt = i >> 5, j = i & 31;
        sBC[tt][j] = xdbl[(rowbase + tt) * 96 + 64 + j];
    }

    float A2[16];
    {
        float al[16];
        #pragma unroll
        for (int q = 0; q < 4; ++q)
            *(float4*)&al[4 * q] = *(const float4*)&A_log[(size_t)d * 16 + 4 * q];
        #pragma unroll
        for (int n = 0; n < 16; ++n) A2[n] = -expf(al[n]) * 1.44269504f;
    }
    const float Dd = Dvec[d];

    float h[16];
    {
        size_t base = ((size_t)(b * CF + c) * 2048 + d) * 16;
        #pragma unroll
        for (int q = 0; q < 4; ++q)
            *(float4*)&h[4 * q] = *(const float4*)&Hin[base + 4 * q];
    }
    __syncthreads();

    #pragma unroll 2
    for (int t = 0; t < CLEN; ++t) {
        size_t r = rowbase + t;
        float dtv = bf2f(dtb[r * 2048 + d]);
        float uv  = bf2f(uc [r * 2048 + d]);
        float zv  = bf2f(zb [r * 2048 + d]);
        float dtu = dtv * uv;
        float bl[16], cl[16];
        #pragma unroll
        for (int q = 0; q < 4; ++q) {
            *(float4*)&bl[4 * q] = *(const float4*)&sBC[t][4 * q];
            *(float4*)&cl[4 * q] = *(const float4*)&sBC[t][16 + 4 * q];
        }
        float acc = uv * Dd;
        #pragma unroll
        for (int n = 0; n < 16; ++n) {
            h[n] = exp2f(dtv * A2[n]) * h[n] + dtu * bl[n];
            acc += h[n] * cl[n];
        }
        float yv = acc * zv / (1.f + expf(-zv));
        yb[r * 2048 + d] = f2bf(yv);
    }
}

extern "C" void kernel_launch(void* const* d_in, const int* in_sizes, int n_in,
                              void* d_out, int out_size, void* d_ws, size_t ws_size,
                              hipStream_t stream)
{
    const float* x      = (const float*)d_in[0];
    const float* W_in   = (const float*)d_in[1];
    const float* conv_w = (const float*)d_in[2];
    const float* conv_b = (const float*)d_in[3];
    const float* W_x    = (const float*)d_in[4];
    const float* W_dt   = (const float*)d_in[5];
    const float* b_dt   = (const float*)d_in[6];
    const float* A_log  = (const float*)d_in[7];
    const float* Dv     = (const float*)d_in[8];
    const float* W_out  = (const float*)d_in[9];
    float* out = (float*)d_out;

    float* ws    = (float*)d_ws;
    float* upre  = ws;                       // [2048][2048] f32 (GEMM1 u half)
    unsigned short* dtb = (unsigned short*)upre;  // ALIAS: dt (bf16) overwrites
                                             //   u_pre (dead after conv)
    unsigned short* uc = (unsigned short*)(ws + 4194304);  // [2048][2048] bf16
    float* xdbl  = ws + 4194304 + 2097152;   // [2048][96]   f32
    float* Hend  = xdbl + 196608;            // [2][CF][2048][16] = 2097152
    float* Hin   = Hend + 2097152;           // 2097152
    float* Sdt   = Hin + 2097152;            // [2][CF][2048] = 131072
    float* part  = Hend;                     // ALIAS: [16][2048][96] = 3145728
                                             //   (dead before pass1/pass2)
    unsigned short* zb   = (unsigned short*)(Sdt + 131072);  // [2048][2048] bf16
    unsigned short* xb   = zb + 4194304;     // [2048][1024] bf16
    unsigned short* wbT  = xb + 2097152;     // [4096][1024] bf16 (W_in^T)
    unsigned short* wobT = wbT + 4194304;    // [1024][2048] bf16 (W_out^T)
    unsigned short* yb   = wbT;              // aliases wbT (dead after GEMM1)

    dim3 blk(256);

    // prep
    transpose_cast<<<dim3(128, 32), blk, 0, stream>>>(W_in, wbT, 1024, 4096);
    transpose_cast<<<dim3(32, 64), blk, 0, stream>>>(W_out, wobT, 2048, 1024);
    cast_bf16<<<2048, blk, 0, stream>>>(x, xb);

    // 1. xz = x @ W_in   (bf16 MFMA; split epilogue: u fp32, z bf16)
    gemm_bf16_v2<128, 128><<<dim3(32, 16), blk, 0, stream>>>(
        xb, wbT, upre, zb, 1024, 1024, 1024, 0, 2048);

    // 2. u_c = silu(conv(u) + cb) -> bf16
    conv_silu_kernel<<<(2048 * 2048) / 256, blk, 0, stream>>>(upre, conv_w, conv_b, uc);

    // 3. x_dbl = u_c @ W_x   (split-K, bf16 A, partials + reduce)
    gemm_f32_splitk<<<512, blk, 0, stream>>>(uc, W_x, part);
    reduce_splitk<<<192, blk, 0, stream>>>(part, xdbl);

    // 4. dt = softplus(x_dbl[:, :64] @ W_dt + b_dt) -> bf16 (aliases upre)
    gemm_f32<<<dim3(32, 32), blk, 0, stream>>>(
        xdbl, W_dt, (float*)dtb, 2048, 2048, 64, 96, 2048, 2048, 1, b_dt);

    // 5. register-state chunk scan
    scan_pass1<<<512, blk, 0, stream>>>(uc, dtb, xdbl, A_log, Hend, Sdt);
    scan_pass2<<<256, blk, 0, stream>>>(Hend, Sdt, A_log, Hin);
    scan_pass3<<<512, blk, 0, stream>>>(uc, dtb, zb, xdbl, A_log, Dv, Hin, yb);

    // 6. out = y @ W_out   (bf16 MFMA, 64x64 tile -> 512 blocks)
    gemm_bf16_v2<64, 64><<<dim3(16, 32), blk, 0, stream>>>(
        yb, wobT, out, nullptr, 2048, 2048, 2048, 1024, 0);
}